// Round 7
// baseline (449.781 us; speedup 1.0000x reference)
//
#include <hip/hip_runtime.h>
#include <hip/hip_bf16.h>

#define BB 8
#define CC 64
#define HH 64
#define WW 64
#define LL 4096
#define DI 128
#define KK 4
#define NN 16
#define RR 4
#define XD 36   // R + 2N
#define GG 64   // scan chunks
#define TT 64   // timesteps per chunk

__device__ __forceinline__ float softplusf(float x){
    return fmaxf(x, 0.f) + __logf(1.f + __expf(-fabsf(x)));
}
__device__ __forceinline__ int p_of(int k, int t){
    int tt = (k & 2) ? (LL - 1 - t) : t;
    return (k & 1) ? ((tt & 63) * 64 + (tt >> 6)) : tt;
}

// DPP butterfly add
template<int CTRL>
__device__ __forceinline__ float dpp_xadd(float v){
    int t = __builtin_amdgcn_update_dpp(0, __float_as_int(v), CTRL, 0xF, 0xF, true);
    return v + __int_as_float(t);
}

// ---------------- K1: LN(C) + in_proj, 64-pixel-tile LDS GEMM
__global__ __launch_bounds__(256) void k1_ln_inproj(
    const float* __restrict__ x,     // (B,C,L)
    const float* __restrict__ ln1_g,
    const float* __restrict__ ln1_b,
    const float* __restrict__ ipw,   // (256,64)
    const float* __restrict__ ipb,   // (256)
    float* __restrict__ xi, float* __restrict__ zs)
{
    int bid = blockIdx.x;            // b*64 + ptile
    int b = bid >> 6, p0 = (bid & 63)*64;
    int tid = threadIdx.x;

    __shared__ float xs[64*65];      // xs[pix][c]
    __shared__ float lnxT[64*68];    // lnxT[c][pix]
    __shared__ float wT[16*260];     // chunk weights wT[k][d]
    __shared__ float gb[128];
    __shared__ float bias[256];
    __shared__ float red[512];
    __shared__ float mv[128];

    if (tid < 128) gb[tid] = (tid < 64) ? ln1_g[tid] : ln1_b[tid - 64];
    bias[tid] = ipb[tid];

    #pragma unroll
    for (int it = 0; it < 4; it++){
        int i = tid + it*256;        // 1024 float4
        int c = i >> 4, pq = i & 15;
        float4 v = *(const float4*)(x + ((size_t)(b*CC + c))*LL + p0 + pq*4);
        xs[(pq*4+0)*65 + c] = v.x;
        xs[(pq*4+1)*65 + c] = v.y;
        xs[(pq*4+2)*65 + c] = v.z;
        xs[(pq*4+3)*65 + c] = v.w;
    }
    __syncthreads();

    {
        int pix = tid >> 2, q = tid & 3;
        float s = 0.f, sq = 0.f;
        #pragma unroll
        for (int cc = 0; cc < 16; cc++){
            float v = xs[pix*65 + q*16 + cc];
            s += v; sq = fmaf(v, v, sq);
        }
        red[tid*2] = s; red[tid*2+1] = sq;
    }
    __syncthreads();
    if (tid < 64){
        float s = red[tid*8] + red[tid*8+2] + red[tid*8+4] + red[tid*8+6];
        float sq = red[tid*8+1] + red[tid*8+3] + red[tid*8+5] + red[tid*8+7];
        float mean = s * (1.f/64.f);
        float var  = sq * (1.f/64.f) - mean*mean;
        mv[tid*2] = mean; mv[tid*2+1] = rsqrtf(var + 1e-5f);
    }
    __syncthreads();
    {
        int pix = tid >> 2, q = tid & 3;
        float mean = mv[pix*2], rstd = mv[pix*2+1];
        #pragma unroll
        for (int cc = 0; cc < 16; cc++){
            int c = q*16 + cc;
            float v = (xs[pix*65 + c] - mean)*rstd*gb[c] + gb[64+c];
            lnxT[c*68 + pix] = v;
        }
    }

    int pt = tid >> 4, ot = tid & 15;
    float acc[16][4];
    #pragma unroll
    for (int j = 0; j < 16; j++)
        #pragma unroll
        for (int i2 = 0; i2 < 4; i2++) acc[j][i2] = 0.f;

    for (int kc = 0; kc < 4; kc++){
        __syncthreads();
        #pragma unroll
        for (int it = 0; it < 4; it++){
            int i = tid + it*256;
            int d = i >> 2, jq = i & 3;
            float4 wv = *(const float4*)(ipw + d*64 + kc*16 + jq*4);
            wT[(jq*4+0)*260 + d] = wv.x;
            wT[(jq*4+1)*260 + d] = wv.y;
            wT[(jq*4+2)*260 + d] = wv.z;
            wT[(jq*4+3)*260 + d] = wv.w;
        }
        __syncthreads();
        #pragma unroll
        for (int k = 0; k < 16; k++){
            float4 rv = *(const float4*)(lnxT + (kc*16 + k)*68 + pt*4);
            #pragma unroll
            for (int g = 0; g < 4; g++){
                float4 wv = *(const float4*)(wT + k*260 + g*64 + ot*4);
                acc[g*4+0][0] = fmaf(wv.x, rv.x, acc[g*4+0][0]);
                acc[g*4+0][1] = fmaf(wv.x, rv.y, acc[g*4+0][1]);
                acc[g*4+0][2] = fmaf(wv.x, rv.z, acc[g*4+0][2]);
                acc[g*4+0][3] = fmaf(wv.x, rv.w, acc[g*4+0][3]);
                acc[g*4+1][0] = fmaf(wv.y, rv.x, acc[g*4+1][0]);
                acc[g*4+1][1] = fmaf(wv.y, rv.y, acc[g*4+1][1]);
                acc[g*4+1][2] = fmaf(wv.y, rv.z, acc[g*4+1][2]);
                acc[g*4+1][3] = fmaf(wv.y, rv.w, acc[g*4+1][3]);
                acc[g*4+2][0] = fmaf(wv.z, rv.x, acc[g*4+2][0]);
                acc[g*4+2][1] = fmaf(wv.z, rv.y, acc[g*4+2][1]);
                acc[g*4+2][2] = fmaf(wv.z, rv.z, acc[g*4+2][2]);
                acc[g*4+2][3] = fmaf(wv.z, rv.w, acc[g*4+2][3]);
                acc[g*4+3][0] = fmaf(wv.w, rv.x, acc[g*4+3][0]);
                acc[g*4+3][1] = fmaf(wv.w, rv.y, acc[g*4+3][1]);
                acc[g*4+3][2] = fmaf(wv.w, rv.z, acc[g*4+3][2]);
                acc[g*4+3][3] = fmaf(wv.w, rv.w, acc[g*4+3][3]);
            }
        }
    }

    #pragma unroll
    for (int i2 = 0; i2 < 4; i2++){
        size_t prow = ((size_t)(b*LL) + p0 + pt*4 + i2);
        #pragma unroll
        for (int g = 0; g < 4; g++){
            int dbase = g*64 + ot*4;
            float4 v;
            v.x = acc[g*4+0][i2] + bias[dbase+0];
            v.y = acc[g*4+1][i2] + bias[dbase+1];
            v.z = acc[g*4+2][i2] + bias[dbase+2];
            v.w = acc[g*4+3][i2] + bias[dbase+3];
            if (g < 2){
                *(float4*)(xi + prow*DI + dbase) = v;
            } else {
                v.x = v.x / (1.f + __expf(-v.x));
                v.y = v.y / (1.f + __expf(-v.y));
                v.z = v.z / (1.f + __expf(-v.z));
                v.w = v.w / (1.f + __expf(-v.w));
                *(float4*)(zs + prow*DI + dbase - 128) = v;
            }
        }
    }
}

// ---------------- K2: depthwise 3x3 + SiLU, 4 pixels/thread
__global__ __launch_bounds__(256) void k2_dwconv(
    const float* __restrict__ xi,
    const float* __restrict__ cw,   // (128,3,3)
    const float* __restrict__ cb,
    float* __restrict__ xc)
{
    int idx = blockIdx.x*256 + threadIdx.x;   // 1,048,576 threads
    int d = idx & 127;
    int g = idx >> 7;                // pixel group (4 consecutive w)
    int p0 = (g & 1023) * 4;
    int b = g >> 10;
    int h = p0 >> 6, w0 = p0 & 63;
    float wt[9];
    #pragma unroll
    for (int j = 0; j < 9; j++) wt[j] = cw[d*9 + j];
    float bv = cb[d];
    float acc[4] = {bv, bv, bv, bv};
    #pragma unroll
    for (int ky = 0; ky < 3; ky++){
        int hh = h + ky - 1;
        if ((unsigned)hh >= 64u) continue;
        const float* row = xi + ((size_t)(b*LL) + hh*64)*DI + d;
        float v0 = (w0 > 0)  ? row[(w0-1)*DI] : 0.f;
        float v1 = row[(w0+0)*DI];
        float v2 = row[(w0+1)*DI];
        float v3 = row[(w0+2)*DI];
        float v4 = row[(w0+3)*DI];
        float v5 = (w0 < 60) ? row[(w0+4)*DI] : 0.f;
        float wa = wt[ky*3], wbv = wt[ky*3+1], wc = wt[ky*3+2];
        acc[0] = fmaf(v0, wa, fmaf(v1, wbv, fmaf(v2, wc, acc[0])));
        acc[1] = fmaf(v1, wa, fmaf(v2, wbv, fmaf(v3, wc, acc[1])));
        acc[2] = fmaf(v2, wa, fmaf(v3, wbv, fmaf(v4, wc, acc[2])));
        acc[3] = fmaf(v3, wa, fmaf(v4, wbv, fmaf(v5, wc, acc[3])));
    }
    #pragma unroll
    for (int i = 0; i < 4; i++){
        float a = acc[i];
        float sg = 1.f / (1.f + __expf(-a));
        xc[((size_t)(b*LL) + p0 + i)*DI + d] = a * sg;
    }
}

// ---------------- K3: x_dbl = xproj(xc), register-tiled LDS GEMM
__global__ __launch_bounds__(256) void k3_xdbl(
    const float* __restrict__ xc,
    const float* __restrict__ xpw,   // (144,128)
    float* __restrict__ xdbl)
{
    int bid = blockIdx.x;
    int b = bid >> 6, ptile = bid & 63;
    int tid = threadIdx.x;
    int ot = tid & 15;
    int pt = tid >> 4;

    __shared__ float r[64*132];
    __shared__ float wT[32*192];

    const float* xcb = xc + ((size_t)(b*LL) + ptile*64)*DI;
    for (int i = tid; i < 2048; i += 256){
        int pix = i >> 5, kq = i & 31;
        float4 v = *(const float4*)(xcb + pix*128 + kq*4);
        *(float4*)(r + pix*132 + kq*4) = v;
    }

    float acc[9][4];
    #pragma unroll
    for (int j = 0; j < 9; j++)
        #pragma unroll
        for (int i2 = 0; i2 < 4; i2++) acc[j][i2] = 0.f;

    for (int kc = 0; kc < 4; kc++){
        __syncthreads();
        int k0 = kc*32;
        for (int i = tid; i < 1152; i += 256){
            int cl = i >> 3, jq = i & 7;
            float4 wv = *(const float4*)(xpw + cl*128 + k0 + jq*4);
            int o = (cl*456) >> 12;
            int j = cl - o*9;
            wT[(jq*4+0)*192 + o*12 + j] = wv.x;
            wT[(jq*4+1)*192 + o*12 + j] = wv.y;
            wT[(jq*4+2)*192 + o*12 + j] = wv.z;
            wT[(jq*4+3)*192 + o*12 + j] = wv.w;
        }
        __syncthreads();
        const float* rbase = r + (pt*4)*132 + k0;
        #pragma unroll 4
        for (int k = 0; k < 32; k++){
            float4 wa = *(const float4*)(wT + k*192 + ot*12);
            float4 wb = *(const float4*)(wT + k*192 + ot*12 + 4);
            float w8 = wT[k*192 + ot*12 + 8];
            float rv0 = rbase[k];
            float rv1 = rbase[132 + k];
            float rv2 = rbase[264 + k];
            float rv3 = rbase[396 + k];
            float wv[9] = {wa.x, wa.y, wa.z, wa.w, wb.x, wb.y, wb.z, wb.w, w8};
            float rv[4] = {rv0, rv1, rv2, rv3};
            #pragma unroll
            for (int j = 0; j < 9; j++)
                #pragma unroll
                for (int i2 = 0; i2 < 4; i2++)
                    acc[j][i2] = fmaf(wv[j], rv[i2], acc[j][i2]);
        }
    }

    int kd = ot >> 2;
    int cbase = (ot & 3)*9;
    size_t obase = ((size_t)(b*KK + kd))*LL;
    #pragma unroll
    for (int i2 = 0; i2 < 4; i2++){
        int p = ptile*64 + pt*4 + i2;
        int tT = (p & 63)*64 + (p >> 6);
        int t = (kd == 0) ? p : (kd == 1) ? tT : (kd == 2) ? (4095 - p) : (4095 - tT);
        float* dst = xdbl + (obase + t)*XD + cbase;
        #pragma unroll
        for (int j = 0; j < 9; j++) dst[j] = acc[j][i2];
    }
}

// ---------------- K4a: per-chunk local scan -> H, P (pair-lane split: 8 states/thread)
__global__ __launch_bounds__(256, 8) void k4a_local(
    const float* __restrict__ xc, const float* __restrict__ xdbl,
    const float* __restrict__ dtw, const float* __restrict__ dtb,
    const float* __restrict__ A_logs,
    float* __restrict__ Pbuf, float* __restrict__ Hbuf)
{
    int bid = blockIdx.x;            // ((b*4+k)*64+cc)
    int cc = bid & 63, k = (bid >> 6) & 3, b = bid >> 8;
    int tid = threadIdx.x;
    int d = tid >> 1, half = tid & 1;
    int kd = k*DI + d;
    float4 wv4 = *(const float4*)(dtw + kd*4);
    float bias = dtb[kd];
    float An2[8];
    {
        const float4* al = (const float4*)(A_logs + kd*16 + half*8);
        #pragma unroll
        for (int i = 0; i < 2; i++){
            float4 a = al[i];
            An2[i*4+0] = -__expf(a.x) * 1.44269504f;
            An2[i*4+1] = -__expf(a.y) * 1.44269504f;
            An2[i*4+2] = -__expf(a.z) * 1.44269504f;
            An2[i*4+3] = -__expf(a.w) * 1.44269504f;
        }
    }
    __shared__ float sraw[TT*XD];
    const float* src = xdbl + ((size_t)(b*KK + k)*LL + cc*TT)*XD;
    for (int i = tid; i < TT*XD/4; i += 256)
        ((float4*)sraw)[i] = ((const float4*)src)[i];
    __syncthreads();

    const float* xcb = xc + (size_t)b*LL*DI;
    float h[8];
    #pragma unroll
    for (int i = 0; i < 8; i++) h[i] = 0.f;
    float Sdt = 0.f;
    for (int t = 0; t < TT; t++){
        const float* rp = sraw + t*XD;
        float4 xr = *(const float4*)rp;
        float dtr = fmaf(xr.x, wv4.x, fmaf(xr.y, wv4.y, fmaf(xr.z, wv4.z, fmaf(xr.w, wv4.w, bias))));
        float dt = softplusf(dtr);
        Sdt += dt;
        int p = p_of(k, cc*TT + t);
        float u = xcb[(size_t)p*DI + d];
        float du = dt * u;
        float4 B0 = *(const float4*)(rp + 4 + half*8);
        float4 B1 = *(const float4*)(rp + 8 + half*8);
        h[0] = fmaf(h[0], exp2f(dt*An2[0]), du*B0.x);
        h[1] = fmaf(h[1], exp2f(dt*An2[1]), du*B0.y);
        h[2] = fmaf(h[2], exp2f(dt*An2[2]), du*B0.z);
        h[3] = fmaf(h[3], exp2f(dt*An2[3]), du*B0.w);
        h[4] = fmaf(h[4], exp2f(dt*An2[4]), du*B1.x);
        h[5] = fmaf(h[5], exp2f(dt*An2[5]), du*B1.y);
        h[6] = fmaf(h[6], exp2f(dt*An2[6]), du*B1.z);
        h[7] = fmaf(h[7], exp2f(dt*An2[7]), du*B1.w);
    }
    size_t ob = ((size_t)bid)*2048 + d*16 + half*8;
    #pragma unroll
    for (int i = 0; i < 8; i++){
        Pbuf[ob + i] = exp2f(An2[i] * Sdt);
        Hbuf[ob + i] = h[i];
    }
}

// ---------------- K4b: chunk-boundary propagation
__global__ __launch_bounds__(256) void k4b_prop(
    const float* __restrict__ Pbuf, const float* __restrict__ Hbuf,
    float* __restrict__ hin_buf)
{
    int chain = blockIdx.x*256 + threadIdx.x;
    int bk = chain >> 11, s = chain & 2047;
    float hin = 0.f;
    for (int c = 0; c < GG; c++){
        size_t idx = ((size_t)(bk*GG + c))*2048 + s;
        hin_buf[idx] = hin;
        hin = fmaf(Pbuf[idx], hin, Hbuf[idx]);
    }
}

// ---------------- K4c: per-chunk re-scan seeded with hin, emit y (pair-lane split)
__global__ __launch_bounds__(256, 6) void k4c_emit(
    const float* __restrict__ xc, const float* __restrict__ xdbl,
    const float* __restrict__ dtw, const float* __restrict__ dtb,
    const float* __restrict__ A_logs, const float* __restrict__ Ds,
    const float* __restrict__ hin_buf,
    float* __restrict__ y)
{
    int bid = blockIdx.x;
    int cc = bid & 63, k = (bid >> 6) & 3, b = bid >> 8;
    int tid = threadIdx.x;
    int d = tid >> 1, half = tid & 1;
    int kd = k*DI + d;
    float4 wv4 = *(const float4*)(dtw + kd*4);
    float bias = dtb[kd];
    float Dv = Ds[kd];
    float An2[8];
    {
        const float4* al = (const float4*)(A_logs + kd*16 + half*8);
        #pragma unroll
        for (int i = 0; i < 2; i++){
            float4 a = al[i];
            An2[i*4+0] = -__expf(a.x) * 1.44269504f;
            An2[i*4+1] = -__expf(a.y) * 1.44269504f;
            An2[i*4+2] = -__expf(a.z) * 1.44269504f;
            An2[i*4+3] = -__expf(a.w) * 1.44269504f;
        }
    }
    __shared__ float sraw[TT*XD];
    const float* src = xdbl + ((size_t)(b*KK + k)*LL + cc*TT)*XD;
    for (int i = tid; i < TT*XD/4; i += 256)
        ((float4*)sraw)[i] = ((const float4*)src)[i];
    __syncthreads();

    const float* xcb = xc + (size_t)b*LL*DI;
    float* yb = y + (size_t)b*LL*DI;
    float h[8];
    {
        const float4* hi = (const float4*)(hin_buf + ((size_t)bid)*2048 + d*16 + half*8);
        float4 a0 = hi[0], a1 = hi[1];
        h[0]=a0.x; h[1]=a0.y; h[2]=a0.z; h[3]=a0.w;
        h[4]=a1.x; h[5]=a1.y; h[6]=a1.z; h[7]=a1.w;
    }
    for (int t = 0; t < TT; t++){
        const float* rp = sraw + t*XD;
        float4 xr = *(const float4*)rp;
        float dtr = fmaf(xr.x, wv4.x, fmaf(xr.y, wv4.y, fmaf(xr.z, wv4.z, fmaf(xr.w, wv4.w, bias))));
        float dt = softplusf(dtr);
        int p = p_of(k, cc*TT + t);
        float u = xcb[(size_t)p*DI + d];
        float du = dt * u;
        float4 B0 = *(const float4*)(rp + 4 + half*8);
        float4 B1 = *(const float4*)(rp + 8 + half*8);
        float4 C0 = *(const float4*)(rp + 20 + half*8);
        float4 C1 = *(const float4*)(rp + 24 + half*8);
        float yv = half ? 0.f : Dv * u;
        h[0] = fmaf(h[0], exp2f(dt*An2[0]), du*B0.x); yv = fmaf(h[0], C0.x, yv);
        h[1] = fmaf(h[1], exp2f(dt*An2[1]), du*B0.y); yv = fmaf(h[1], C0.y, yv);
        h[2] = fmaf(h[2], exp2f(dt*An2[2]), du*B0.z); yv = fmaf(h[2], C0.z, yv);
        h[3] = fmaf(h[3], exp2f(dt*An2[3]), du*B0.w); yv = fmaf(h[3], C0.w, yv);
        h[4] = fmaf(h[4], exp2f(dt*An2[4]), du*B1.x); yv = fmaf(h[4], C1.x, yv);
        h[5] = fmaf(h[5], exp2f(dt*An2[5]), du*B1.y); yv = fmaf(h[5], C1.y, yv);
        h[6] = fmaf(h[6], exp2f(dt*An2[6]), du*B1.z); yv = fmaf(h[6], C1.z, yv);
        h[7] = fmaf(h[7], exp2f(dt*An2[7]), du*B1.w); yv = fmaf(h[7], C1.w, yv);
        yv = dpp_xadd<0xB1>(yv);     // combine the two halves (lane pair)
        if (half == 0)
            atomicAdd(&yb[(size_t)p*DI + d], yv);
    }
}

// ---------------- K4 serial fallback (used if ws too small)
__global__ __launch_bounds__(256) void k4_scan(
    const float* __restrict__ xc, const float* __restrict__ xdbl,
    const float* __restrict__ dtw, const float* __restrict__ dtb,
    const float* __restrict__ A_logs, const float* __restrict__ Ds,
    float* __restrict__ y)
{
    int bid = blockIdx.x;
    int b = bid >> 5, k = (bid >> 3) & 3, grp = bid & 7;
    int d0 = grp * 16;
    int tid = threadIdx.x;
    int wv = tid >> 6, lane = tid & 63, n = lane & 15, j = lane >> 4;
    int ch = wv*4 + j;
    int d = d0 + ch;
    int kd = k*DI + d;
    float An = -__expf(A_logs[kd*NN + n]);
    int ch_s = tid & 15;
    int kds = k*DI + d0 + ch_s;
    float w0s = dtw[kds*4+0], w1s = dtw[kds*4+1], w2s = dtw[kds*4+2], w3s = dtw[kds*4+3];
    float bs  = dtb[kds];
    float Dvs = Ds[kds];
    __shared__ float sraw[64*XD];
    __shared__ float sdd[64*16*2];
    __shared__ float sdy[64*17];
    const float* xdbase = xdbl + (size_t)(b*KK + k)*LL*XD;
    const float* xcb = xc + (size_t)b*LL*DI;
    float* yb = y + (size_t)b*LL*DI;
    float h = 0.f;
    for (int cc = 0; cc < 64; cc++){
        __syncthreads();
        const float* src = xdbase + (size_t)cc*64*XD;
        for (int i2 = tid; i2 < 576; i2 += 256)
            ((float4*)sraw)[i2] = ((const float4*)src)[i2];
        #pragma unroll
        for (int it = 0; it < 4; it++){
            int idx = tid + it*256;
            int t = idx >> 4;
            int pu = p_of(k, cc*64 + t);
            float u = xcb[(size_t)pu*DI + d0 + ch_s];
            float4 xr = *(const float4*)(src + t*XD);
            float dtr = fmaf(xr.x, w0s, fmaf(xr.y, w1s, fmaf(xr.z, w2s, fmaf(xr.w, w3s, bs))));
            float dt = softplusf(dtr);
            sdd[idx*2]     = dt;
            sdd[idx*2 + 1] = dt*u;
            sdy[t*17 + ch_s] = Dvs * u;
        }
        __syncthreads();
        #pragma unroll
        for (int tg = 0; tg < 4; tg++){
            float myv = 0.f;
            #pragma unroll
            for (int it = 0; it < 16; it++){
                int t = tg*16 + it;
                float dt = sdd[(t*16 + ch)*2];
                float du = sdd[(t*16 + ch)*2 + 1];
                float Bn = sraw[t*XD + 4 + n];
                float Cn = sraw[t*XD + 20 + n];
                float e = __expf(dt * An);
                h = fmaf(h, e, du * Bn);
                float yv = h * Cn;
                yv = dpp_xadd<0xB1>(yv);
                yv = dpp_xadd<0x4E>(yv);
                yv = dpp_xadd<0x141>(yv);
                yv = dpp_xadd<0x140>(yv);
                if (it == n) myv = yv;
            }
            int t = tg*16 + n;
            float yt = myv + sdy[t*17 + ch];
            int p = p_of(k, cc*64 + t);
            atomicAdd(&yb[(size_t)p*DI + d], yt);
        }
    }
}

// ---------------- K5: LN(DI)*silu(z) + out_proj + residual + fused channel-LN
// writes xo (B,L,C) and cl (B,L,C); k6 eliminated
__global__ __launch_bounds__(256) void k5_out(
    const float* __restrict__ y, const float* __restrict__ zs,
    const float* __restrict__ on_g, const float* __restrict__ on_b,
    const float* __restrict__ opw,  // (64,128)
    const float* __restrict__ opb,
    const float* __restrict__ x,    // (B,C,L)
    const float* __restrict__ cn_g, const float* __restrict__ cn_b,
    float* __restrict__ xo, float* __restrict__ cl)
{
    int bid = blockIdx.x;
    int b = bid >> 6, p0 = (bid & 63)*64;
    int tid = threadIdx.x;

    __shared__ float vT[128*68];     // vT[d][pix]
    __shared__ float wT[128*68];     // wT[d][c]
    __shared__ float gb[256];        // on_g 0..127, on_b 128..255
    __shared__ float ob[64];
    __shared__ float cgb[128];       // cn_g 0..63, cn_b 64..127
    __shared__ float red[2048];
    __shared__ float mv[128];

    gb[tid] = (tid < 128) ? on_g[tid] : on_b[tid - 128];
    if (tid < 64) ob[tid] = opb[tid];
    if (tid >= 128 && tid < 256) cgb[tid-128] = (tid < 192) ? cn_g[tid-128] : cn_b[tid-192];

    #pragma unroll
    for (int it = 0; it < 8; it++){
        int i = tid + it*256;
        int c = i >> 5, jq = i & 31;
        float4 wv = *(const float4*)(opw + c*128 + jq*4);
        wT[(jq*4+0)*68 + c] = wv.x;
        wT[(jq*4+1)*68 + c] = wv.y;
        wT[(jq*4+2)*68 + c] = wv.z;
        wT[(jq*4+3)*68 + c] = wv.w;
    }

    int pix = tid >> 2, q = tid & 3;
    size_t base = ((size_t)(b*LL) + p0 + pix)*DI + q*32;
    float yv[32];
    {
        const float4* y4 = (const float4*)(y + base);
        float s = 0.f, sq = 0.f;
        #pragma unroll
        for (int i = 0; i < 8; i++){
            float4 a = y4[i];
            yv[i*4+0] = a.x; yv[i*4+1] = a.y; yv[i*4+2] = a.z; yv[i*4+3] = a.w;
            s += a.x + a.y + a.z + a.w;
            sq = fmaf(a.x,a.x, fmaf(a.y,a.y, fmaf(a.z,a.z, fmaf(a.w,a.w, sq))));
        }
        red[tid*2] = s; red[tid*2+1] = sq;
    }
    __syncthreads();
    if (tid < 64){
        float s = red[tid*8] + red[tid*8+2] + red[tid*8+4] + red[tid*8+6];
        float sq = red[tid*8+1] + red[tid*8+3] + red[tid*8+5] + red[tid*8+7];
        float mean = s * (1.f/128.f);
        float var  = sq * (1.f/128.f) - mean*mean;
        mv[tid*2] = mean; mv[tid*2+1] = rsqrtf(var + 1e-5f);
    }
    __syncthreads();
    {
        float mean = mv[pix*2], rstd = mv[pix*2+1];
        const float4* z4 = (const float4*)(zs + base);
        #pragma unroll
        for (int i = 0; i < 8; i++){
            float4 zz = z4[i];
            float zv[4] = {zz.x, zz.y, zz.z, zz.w};
            #pragma unroll
            for (int jj = 0; jj < 4; jj++){
                int dd = q*32 + i*4 + jj;
                float vn = (yv[i*4+jj] - mean)*rstd*gb[dd] + gb[128+dd];
                vT[dd*68 + pix] = vn * zv[jj];
            }
        }
    }
    __syncthreads();

    int pt = tid >> 4, ot = tid & 15;
    float acc[4][4];
    #pragma unroll
    for (int j = 0; j < 4; j++)
        #pragma unroll
        for (int i2 = 0; i2 < 4; i2++) acc[j][i2] = 0.f;

    #pragma unroll 4
    for (int k = 0; k < 128; k++){
        float4 rv = *(const float4*)(vT + k*68 + pt*4);
        float4 wv = *(const float4*)(wT + k*68 + ot*4);
        acc[0][0] = fmaf(wv.x, rv.x, acc[0][0]); acc[0][1] = fmaf(wv.x, rv.y, acc[0][1]);
        acc[0][2] = fmaf(wv.x, rv.z, acc[0][2]); acc[0][3] = fmaf(wv.x, rv.w, acc[0][3]);
        acc[1][0] = fmaf(wv.y, rv.x, acc[1][0]); acc[1][1] = fmaf(wv.y, rv.y, acc[1][1]);
        acc[1][2] = fmaf(wv.y, rv.z, acc[1][2]); acc[1][3] = fmaf(wv.y, rv.w, acc[1][3]);
        acc[2][0] = fmaf(wv.z, rv.x, acc[2][0]); acc[2][1] = fmaf(wv.z, rv.y, acc[2][1]);
        acc[2][2] = fmaf(wv.z, rv.z, acc[2][2]); acc[2][3] = fmaf(wv.z, rv.w, acc[2][3]);
        acc[3][0] = fmaf(wv.w, rv.x, acc[3][0]); acc[3][1] = fmaf(wv.w, rv.y, acc[3][1]);
        acc[3][2] = fmaf(wv.w, rv.z, acc[3][2]); acc[3][3] = fmaf(wv.w, rv.w, acc[3][3]);
    }

    // bias + residual -> xo values in regs
    #pragma unroll
    for (int jj = 0; jj < 4; jj++){
        int c = ot*4 + jj;
        float4 xr = *(const float4*)(x + ((size_t)(b*CC + c))*LL + p0 + pt*4);
        acc[jj][0] += ob[c] + xr.x;
        acc[jj][1] += ob[c] + xr.y;
        acc[jj][2] += ob[c] + xr.z;
        acc[jj][3] += ob[c] + xr.w;
    }
    #pragma unroll
    for (int i2 = 0; i2 < 4; i2++){
        float4 v = make_float4(acc[0][i2], acc[1][i2], acc[2][i2], acc[3][i2]);
        *(float4*)(xo + ((size_t)(b*LL) + p0 + pt*4 + i2)*CC + ot*4) = v;
    }

    // fused channel-LN -> cl
    __syncthreads();   // red reuse safe
    #pragma unroll
    for (int i2 = 0; i2 < 4; i2++){
        float s = acc[0][i2] + acc[1][i2] + acc[2][i2] + acc[3][i2];
        float sq = fmaf(acc[0][i2],acc[0][i2], fmaf(acc[1][i2],acc[1][i2],
                   fmaf(acc[2][i2],acc[2][i2], acc[3][i2]*acc[3][i2])));
        red[(pt*4 + i2)*16 + ot] = s;
        red[1024 + (pt*4 + i2)*16 + ot] = sq;
    }
    __syncthreads();
    if (tid < 64){
        float s = 0.f, sq = 0.f;
        #pragma unroll
        for (int o = 0; o < 16; o++){
            s += red[tid*16 + o];
            sq += red[1024 + tid*16 + o];
        }
        float mean = s * (1.f/64.f);
        float var  = sq * (1.f/64.f) - mean*mean;
        mv[tid*2] = mean; mv[tid*2+1] = rsqrtf(var + 1e-6f);
    }
    __syncthreads();
    #pragma unroll
    for (int i2 = 0; i2 < 4; i2++){
        float mean = mv[(pt*4+i2)*2], rstd = mv[(pt*4+i2)*2+1];
        float4 v;
        v.x = (acc[0][i2] - mean)*rstd*cgb[ot*4+0] + cgb[64+ot*4+0];
        v.y = (acc[1][i2] - mean)*rstd*cgb[ot*4+1] + cgb[64+ot*4+1];
        v.z = (acc[2][i2] - mean)*rstd*cgb[ot*4+2] + cgb[64+ot*4+2];
        v.w = (acc[3][i2] - mean)*rstd*cgb[ot*4+3] + cgb[64+ot*4+3];
        *(float4*)(cl + ((size_t)(b*LL) + p0 + pt*4 + i2)*CC + ot*4) = v;
    }
}

// ---------------- K7: max pools 2/4/8 for SAFM branches 1..3
__global__ __launch_bounds__(256) void k7_pools(const float* __restrict__ cl, float* __restrict__ pools)
{
    int idx = blockIdx.x*256 + threadIdx.x;
    int g, S, base;
    if (idx < 131072)      { g = 1; S = 32; base = 0; }
    else if (idx < 163840) { g = 2; S = 16; base = 131072; idx -= 131072; }
    else if (idx < 172032) { g = 3; S = 8;  base = 163840; idx -= 163840; }
    else return;
    int pw = idx % S; idx /= S;
    int ph = idx % S; idx /= S;
    int j = idx & 15; int b = idx >> 4;
    int kk = 64 / S;
    int c = g*16 + j;
    float m = -1e30f;
    for (int dy = 0; dy < kk; dy++)
        for (int dx = 0; dx < kk; dx++){
            int h = ph*kk + dy, w = pw*kk + dx;
            m = fmaxf(m, cl[((size_t)(b*LL) + h*64 + w)*CC + c]);
        }
    pools[base + ((size_t)(b*16 + j)*S + ph)*S + pw] = m;
}

// ---------------- K8: SAFM branch depthwise convs -> cat (B,L,C)
__global__ __launch_bounds__(256) void k8_mfr(
    const float* __restrict__ cl, const float* __restrict__ pools,
    const float* __restrict__ mfr_w,  // (4,16,3,3)
    const float* __restrict__ mfr_b,  // (4,16)
    float* __restrict__ cat)
{
    int idx = blockIdx.x*256 + threadIdx.x;
    int c = idx & 63; int bp = idx >> 6;
    int p = bp & 4095, b = bp >> 12;
    int g = c >> 4, j = c & 15;
    int h = p >> 6, w = p & 63;
    float acc = mfr_b[g*16 + j];
    const float* wr = mfr_w + (g*16 + j)*9;
    if (g == 0){
        #pragma unroll
        for (int ky = 0; ky < 3; ky++){
            int hh = h + ky - 1; if ((unsigned)hh >= 64u) continue;
            #pragma unroll
            for (int kx = 0; kx < 3; kx++){
                int ww = w + kx - 1; if ((unsigned)ww >= 64u) continue;
                acc = fmaf(cl[((size_t)(b*LL) + hh*64 + ww)*CC + c], wr[ky*3 + kx], acc);
            }
        }
    } else {
        int S = 64 >> g;
        int ph = h >> g, pw = w >> g;
        int base = (g == 1) ? 0 : ((g == 2) ? 131072 : 163840);
        const float* P = pools + base + (size_t)(b*16 + j)*S*S;
        #pragma unroll
        for (int ky = 0; ky < 3; ky++){
            int hh = ph + ky - 1; if ((unsigned)hh >= (unsigned)S) continue;
            #pragma unroll
            for (int kx = 0; kx < 3; kx++){
                int ww = pw + kx - 1; if ((unsigned)ww >= (unsigned)S) continue;
                acc = fmaf(P[hh*S + ww], wr[ky*3 + kx], acc);
            }
        }
    }
    cat[idx] = acc;
}

// ---------------- K9: 1x1 agg + GELU*cl + residual, tiled GEMM -> out (B,C,L)
__global__ __launch_bounds__(256) void k9_agg(
    const float* __restrict__ cat, const float* __restrict__ cl, const float* __restrict__ xo,
    const float* __restrict__ agw,   // (64,64)
    const float* __restrict__ agb,
    float* __restrict__ out)
{
    int bid = blockIdx.x;
    int b = bid >> 6, p0 = (bid & 63)*64;
    int tid = threadIdx.x;

    __shared__ float catT[64*68];
    __shared__ float wT[64*68];
    __shared__ float ab[64];

    if (tid < 64) ab[tid] = agb[tid];
    #pragma unroll
    for (int it = 0; it < 4; it++){
        int i = tid + it*256;
        int pix = i >> 4, cq = i & 15;
        float4 v = *(const float4*)(cat + ((size_t)(b*LL) + p0 + pix)*CC + cq*4);
        catT[(cq*4+0)*68 + pix] = v.x;
        catT[(cq*4+1)*68 + pix] = v.y;
        catT[(cq*4+2)*68 + pix] = v.z;
        catT[(cq*4+3)*68 + pix] = v.w;
        int o = i >> 4;
        float4 wv = *(const float4*)(agw + o*64 + cq*4);
        wT[(cq*4+0)*68 + o] = wv.x;
        wT[(cq*4+1)*68 + o] = wv.y;
        wT[(cq*4+2)*68 + o] = wv.z;
        wT[(cq*4+3)*68 + o] = wv.w;
    }
    __syncthreads();

    int pt = tid >> 4, ot = tid & 15;
    float acc[4][4];
    #pragma unroll
    for (int j = 0; j < 4; j++)
        #pragma unroll
        for (int i2 = 0; i2 < 4; i2++) acc[j][i2] = 0.f;

    #pragma unroll 4
    for (int k = 0; k < 64; k++){
        float4 rv = *(const float4*)(catT + k*68 + pt*4);
        float4 wv = *(const float4*)(wT + k*68 + ot*4);
        acc[0][0] = fmaf(wv.x, rv.x, acc[0][0]); acc[0][1] = fmaf(wv.x, rv.y, acc[0][1]);
        acc[0][2] = fmaf(wv.x, rv.z, acc[0][2]); acc[0][3] = fmaf(wv.x, rv.w, acc[0][3]);
        acc[1][0] = fmaf(wv.y, rv.x, acc[1][0]); acc[1][1] = fmaf(wv.y, rv.y, acc[1][1]);
        acc[1][2] = fmaf(wv.y, rv.z, acc[1][2]); acc[1][3] = fmaf(wv.y, rv.w, acc[1][3]);
        acc[2][0] = fmaf(wv.z, rv.x, acc[2][0]); acc[2][1] = fmaf(wv.z, rv.y, acc[2][1]);
        acc[2][2] = fmaf(wv.z, rv.z, acc[2][2]); acc[2][3] = fmaf(wv.z, rv.w, acc[2][3]);
        acc[3][0] = fmaf(wv.w, rv.x, acc[3][0]); acc[3][1] = fmaf(wv.w, rv.y, acc[3][1]);
        acc[3][2] = fmaf(wv.w, rv.z, acc[3][2]); acc[3][3] = fmaf(wv.w, rv.w, acc[3][3]);
    }

    float res[4][4];
    #pragma unroll
    for (int i2 = 0; i2 < 4; i2++){
        size_t prow = ((size_t)(b*LL) + p0 + pt*4 + i2)*CC + ot*4;
        float4 clv = *(const float4*)(cl + prow);
        float4 xov = *(const float4*)(xo + prow);
        float cla[4] = {clv.x, clv.y, clv.z, clv.w};
        float xoa[4] = {xov.x, xov.y, xov.z, xov.w};
        #pragma unroll
        for (int jj = 0; jj < 4; jj++){
            float av = acc[jj][i2] + ab[ot*4 + jj];
            float gl = 0.5f*av*(1.f + erff(av*0.70710678118f));
            res[jj][i2] = xoa[jj] + gl*cla[jj];
        }
    }
    #pragma unroll
    for (int jj = 0; jj < 4; jj++){
        int o = ot*4 + jj;
        float4 v = make_float4(res[jj][0], res[jj][1], res[jj][2], res[jj][3]);
        *(float4*)(out + ((size_t)(b*CC + o))*LL + p0 + pt*4) = v;
    }
}

extern "C" void kernel_launch(void* const* d_in, const int* in_sizes, int n_in,
                              void* d_out, int out_size, void* d_ws, size_t ws_size,
                              hipStream_t stream)
{
    const float* x       = (const float*)d_in[0];
    const float* ln1_g   = (const float*)d_in[1];
    const float* ln1_b   = (const float*)d_in[2];
    const float* ipw     = (const float*)d_in[3];
    const float* ipb     = (const float*)d_in[4];
    const float* conv_w  = (const float*)d_in[5];
    const float* conv_b  = (const float*)d_in[6];
    const float* xpw     = (const float*)d_in[7];
    const float* dtw     = (const float*)d_in[8];
    const float* dtb     = (const float*)d_in[9];
    const float* A_logs  = (const float*)d_in[10];
    const float* Ds      = (const float*)d_in[11];
    const float* on_g    = (const float*)d_in[12];
    const float* on_b    = (const float*)d_in[13];
    const float* opw     = (const float*)d_in[14];
    const float* opb     = (const float*)d_in[15];
    const float* mfr_w   = (const float*)d_in[16];
    const float* mfr_b   = (const float*)d_in[17];
    const float* agw     = (const float*)d_in[18];
    const float* agb     = (const float*)d_in[19];
    const float* cn_g    = (const float*)d_in[20];
    const float* cn_b    = (const float*)d_in[21];
    float* out = (float*)d_out;

    float* ws = (float*)d_ws;
    float* xi    = ws;               // reused as y
    float* zs    = ws + 4194304;     // reused as cat
    float* xc    = ws + 8388608;     // reused as xo + pools
    float* xdbl  = ws + 12582912;    // reused as cl
    float* y     = xi;
    float* xo    = xc;
    float* pools = xc + 2097152;
    float* cl    = xdbl;
    float* cat   = zs;
    float* Pbuf  = ws + 17301504;
    float* Hbuf  = ws + 21495808;
    float* hinb  = ws + 25690112;
    bool par = ws_size >= (size_t)29884416 * 4;

    // SS2D
    hipLaunchKernelGGL(k1_ln_inproj, dim3(BB*64), dim3(256), 0, stream,
                       x, ln1_g, ln1_b, ipw, ipb, xi, zs);
    hipLaunchKernelGGL(k2_dwconv, dim3(BB*LL*DI/1024), dim3(256), 0, stream,
                       xi, conv_w, conv_b, xc);
    hipLaunchKernelGGL(k3_xdbl, dim3(BB*64), dim3(256), 0, stream,
                       xc, xpw, xdbl);
    hipMemsetAsync(y, 0, (size_t)BB*LL*DI*sizeof(float), stream);
    if (par){
        hipLaunchKernelGGL(k4a_local, dim3(BB*KK*GG), dim3(256), 0, stream,
                           xc, xdbl, dtw, dtb, A_logs, Pbuf, Hbuf);
        hipLaunchKernelGGL(k4b_prop, dim3(256), dim3(256), 0, stream,
                           Pbuf, Hbuf, hinb);
        hipLaunchKernelGGL(k4c_emit, dim3(BB*KK*GG), dim3(256), 0, stream,
                           xc, xdbl, dtw, dtb, A_logs, Ds, hinb, y);
    } else {
        hipLaunchKernelGGL(k4_scan, dim3(256), dim3(256), 0, stream,
                           xc, xdbl, dtw, dtb, A_logs, Ds, y);
    }
    hipLaunchKernelGGL(k5_out, dim3(BB*64), dim3(256), 0, stream,
                       y, zs, on_g, on_b, opw, opb, x, cn_g, cn_b, xo, cl);
    // SAFM (k6 fused into k5)
    hipLaunchKernelGGL(k7_pools, dim3((172032 + 255)/256), dim3(256), 0, stream,
                       cl, pools);
    hipLaunchKernelGGL(k8_mfr, dim3(BB*LL*CC/256), dim3(256), 0, stream,
                       cl, pools, mfr_w, mfr_b, cat);
    hipLaunchKernelGGL(k9_agg, dim3(BB*64), dim3(256), 0, stream,
                       cat, cl, xo, agw, agb, out);
}

// Round 8
// 363.145 us; speedup vs baseline: 1.2386x; 1.2386x over previous
//
#include <hip/hip_runtime.h>
#include <hip/hip_bf16.h>

#define BB 8
#define CC 64
#define HH 64
#define WW 64
#define LL 4096
#define DI 128
#define KK 4
#define NN 16
#define RR 4
#define XD 36   // R + 2N
#define GG 64   // scan chunks
#define TT 64   // timesteps per chunk

__device__ __forceinline__ float softplusf(float x){
    return fmaxf(x, 0.f) + __logf(1.f + __expf(-fabsf(x)));
}
__device__ __forceinline__ int p_of(int k, int t){
    int tt = (k & 2) ? (LL - 1 - t) : t;
    return (k & 1) ? ((tt & 63) * 64 + (tt >> 6)) : tt;
}

// DPP butterfly add (serial fallback kernel only)
template<int CTRL>
__device__ __forceinline__ float dpp_xadd(float v){
    int t = __builtin_amdgcn_update_dpp(0, __float_as_int(v), CTRL, 0xF, 0xF, true);
    return v + __int_as_float(t);
}

// ---------------- K1: LN(C) + in_proj, 64-pixel-tile LDS GEMM
__global__ __launch_bounds__(256) void k1_ln_inproj(
    const float* __restrict__ x,     // (B,C,L)
    const float* __restrict__ ln1_g,
    const float* __restrict__ ln1_b,
    const float* __restrict__ ipw,   // (256,64)
    const float* __restrict__ ipb,   // (256)
    float* __restrict__ xi, float* __restrict__ zs)
{
    int bid = blockIdx.x;            // b*64 + ptile
    int b = bid >> 6, p0 = (bid & 63)*64;
    int tid = threadIdx.x;

    __shared__ float xs[64*65];      // xs[pix][c]
    __shared__ float lnxT[64*68];    // lnxT[c][pix]
    __shared__ float wT[16*260];     // chunk weights wT[k][d]
    __shared__ float gb[128];
    __shared__ float bias[256];
    __shared__ float red[512];
    __shared__ float mv[128];

    if (tid < 128) gb[tid] = (tid < 64) ? ln1_g[tid] : ln1_b[tid - 64];
    bias[tid] = ipb[tid];

    #pragma unroll
    for (int it = 0; it < 4; it++){
        int i = tid + it*256;        // 1024 float4
        int c = i >> 4, pq = i & 15;
        float4 v = *(const float4*)(x + ((size_t)(b*CC + c))*LL + p0 + pq*4);
        xs[(pq*4+0)*65 + c] = v.x;
        xs[(pq*4+1)*65 + c] = v.y;
        xs[(pq*4+2)*65 + c] = v.z;
        xs[(pq*4+3)*65 + c] = v.w;
    }
    __syncthreads();

    {
        int pix = tid >> 2, q = tid & 3;
        float s = 0.f, sq = 0.f;
        #pragma unroll
        for (int cc = 0; cc < 16; cc++){
            float v = xs[pix*65 + q*16 + cc];
            s += v; sq = fmaf(v, v, sq);
        }
        red[tid*2] = s; red[tid*2+1] = sq;
    }
    __syncthreads();
    if (tid < 64){
        float s = red[tid*8] + red[tid*8+2] + red[tid*8+4] + red[tid*8+6];
        float sq = red[tid*8+1] + red[tid*8+3] + red[tid*8+5] + red[tid*8+7];
        float mean = s * (1.f/64.f);
        float var  = sq * (1.f/64.f) - mean*mean;
        mv[tid*2] = mean; mv[tid*2+1] = rsqrtf(var + 1e-5f);
    }
    __syncthreads();
    {
        int pix = tid >> 2, q = tid & 3;
        float mean = mv[pix*2], rstd = mv[pix*2+1];
        #pragma unroll
        for (int cc = 0; cc < 16; cc++){
            int c = q*16 + cc;
            float v = (xs[pix*65 + c] - mean)*rstd*gb[c] + gb[64+c];
            lnxT[c*68 + pix] = v;
        }
    }

    int pt = tid >> 4, ot = tid & 15;
    float acc[16][4];
    #pragma unroll
    for (int j = 0; j < 16; j++)
        #pragma unroll
        for (int i2 = 0; i2 < 4; i2++) acc[j][i2] = 0.f;

    for (int kc = 0; kc < 4; kc++){
        __syncthreads();
        #pragma unroll
        for (int it = 0; it < 4; it++){
            int i = tid + it*256;
            int d = i >> 2, jq = i & 3;
            float4 wv = *(const float4*)(ipw + d*64 + kc*16 + jq*4);
            wT[(jq*4+0)*260 + d] = wv.x;
            wT[(jq*4+1)*260 + d] = wv.y;
            wT[(jq*4+2)*260 + d] = wv.z;
            wT[(jq*4+3)*260 + d] = wv.w;
        }
        __syncthreads();
        #pragma unroll
        for (int k = 0; k < 16; k++){
            float4 rv = *(const float4*)(lnxT + (kc*16 + k)*68 + pt*4);
            #pragma unroll
            for (int g = 0; g < 4; g++){
                float4 wv = *(const float4*)(wT + k*260 + g*64 + ot*4);
                acc[g*4+0][0] = fmaf(wv.x, rv.x, acc[g*4+0][0]);
                acc[g*4+0][1] = fmaf(wv.x, rv.y, acc[g*4+0][1]);
                acc[g*4+0][2] = fmaf(wv.x, rv.z, acc[g*4+0][2]);
                acc[g*4+0][3] = fmaf(wv.x, rv.w, acc[g*4+0][3]);
                acc[g*4+1][0] = fmaf(wv.y, rv.x, acc[g*4+1][0]);
                acc[g*4+1][1] = fmaf(wv.y, rv.y, acc[g*4+1][1]);
                acc[g*4+1][2] = fmaf(wv.y, rv.z, acc[g*4+1][2]);
                acc[g*4+1][3] = fmaf(wv.y, rv.w, acc[g*4+1][3]);
                acc[g*4+2][0] = fmaf(wv.z, rv.x, acc[g*4+2][0]);
                acc[g*4+2][1] = fmaf(wv.z, rv.y, acc[g*4+2][1]);
                acc[g*4+2][2] = fmaf(wv.z, rv.z, acc[g*4+2][2]);
                acc[g*4+2][3] = fmaf(wv.z, rv.w, acc[g*4+2][3]);
                acc[g*4+3][0] = fmaf(wv.w, rv.x, acc[g*4+3][0]);
                acc[g*4+3][1] = fmaf(wv.w, rv.y, acc[g*4+3][1]);
                acc[g*4+3][2] = fmaf(wv.w, rv.z, acc[g*4+3][2]);
                acc[g*4+3][3] = fmaf(wv.w, rv.w, acc[g*4+3][3]);
            }
        }
    }

    #pragma unroll
    for (int i2 = 0; i2 < 4; i2++){
        size_t prow = ((size_t)(b*LL) + p0 + pt*4 + i2);
        #pragma unroll
        for (int g = 0; g < 4; g++){
            int dbase = g*64 + ot*4;
            float4 v;
            v.x = acc[g*4+0][i2] + bias[dbase+0];
            v.y = acc[g*4+1][i2] + bias[dbase+1];
            v.z = acc[g*4+2][i2] + bias[dbase+2];
            v.w = acc[g*4+3][i2] + bias[dbase+3];
            if (g < 2){
                *(float4*)(xi + prow*DI + dbase) = v;
            } else {
                v.x = v.x / (1.f + __expf(-v.x));
                v.y = v.y / (1.f + __expf(-v.y));
                v.z = v.z / (1.f + __expf(-v.z));
                v.w = v.w / (1.f + __expf(-v.w));
                *(float4*)(zs + prow*DI + dbase - 128) = v;
            }
        }
    }
}

// ---------------- K2: depthwise 3x3 + SiLU, 4 pixels/thread
__global__ __launch_bounds__(256) void k2_dwconv(
    const float* __restrict__ xi,
    const float* __restrict__ cw,   // (128,3,3)
    const float* __restrict__ cb,
    float* __restrict__ xc)
{
    int idx = blockIdx.x*256 + threadIdx.x;
    int d = idx & 127;
    int g = idx >> 7;
    int p0 = (g & 1023) * 4;
    int b = g >> 10;
    int h = p0 >> 6, w0 = p0 & 63;
    float wt[9];
    #pragma unroll
    for (int j = 0; j < 9; j++) wt[j] = cw[d*9 + j];
    float bv = cb[d];
    float acc[4] = {bv, bv, bv, bv};
    #pragma unroll
    for (int ky = 0; ky < 3; ky++){
        int hh = h + ky - 1;
        if ((unsigned)hh >= 64u) continue;
        const float* row = xi + ((size_t)(b*LL) + hh*64)*DI + d;
        float v0 = (w0 > 0)  ? row[(w0-1)*DI] : 0.f;
        float v1 = row[(w0+0)*DI];
        float v2 = row[(w0+1)*DI];
        float v3 = row[(w0+2)*DI];
        float v4 = row[(w0+3)*DI];
        float v5 = (w0 < 60) ? row[(w0+4)*DI] : 0.f;
        float wa = wt[ky*3], wbv = wt[ky*3+1], wc = wt[ky*3+2];
        acc[0] = fmaf(v0, wa, fmaf(v1, wbv, fmaf(v2, wc, acc[0])));
        acc[1] = fmaf(v1, wa, fmaf(v2, wbv, fmaf(v3, wc, acc[1])));
        acc[2] = fmaf(v2, wa, fmaf(v3, wbv, fmaf(v4, wc, acc[2])));
        acc[3] = fmaf(v3, wa, fmaf(v4, wbv, fmaf(v5, wc, acc[3])));
    }
    #pragma unroll
    for (int i = 0; i < 4; i++){
        float a = acc[i];
        float sg = 1.f / (1.f + __expf(-a));
        xc[((size_t)(b*LL) + p0 + i)*DI + d] = a * sg;
    }
}

// ---------------- K3: x_dbl = xproj(xc), register-tiled LDS GEMM
__global__ __launch_bounds__(256) void k3_xdbl(
    const float* __restrict__ xc,
    const float* __restrict__ xpw,   // (144,128)
    float* __restrict__ xdbl)
{
    int bid = blockIdx.x;
    int b = bid >> 6, ptile = bid & 63;
    int tid = threadIdx.x;
    int ot = tid & 15;
    int pt = tid >> 4;

    __shared__ float r[64*132];
    __shared__ float wT[32*192];

    const float* xcb = xc + ((size_t)(b*LL) + ptile*64)*DI;
    for (int i = tid; i < 2048; i += 256){
        int pix = i >> 5, kq = i & 31;
        float4 v = *(const float4*)(xcb + pix*128 + kq*4);
        *(float4*)(r + pix*132 + kq*4) = v;
    }

    float acc[9][4];
    #pragma unroll
    for (int j = 0; j < 9; j++)
        #pragma unroll
        for (int i2 = 0; i2 < 4; i2++) acc[j][i2] = 0.f;

    for (int kc = 0; kc < 4; kc++){
        __syncthreads();
        int k0 = kc*32;
        for (int i = tid; i < 1152; i += 256){
            int cl = i >> 3, jq = i & 7;
            float4 wv = *(const float4*)(xpw + cl*128 + k0 + jq*4);
            int o = (cl*456) >> 12;
            int j = cl - o*9;
            wT[(jq*4+0)*192 + o*12 + j] = wv.x;
            wT[(jq*4+1)*192 + o*12 + j] = wv.y;
            wT[(jq*4+2)*192 + o*12 + j] = wv.z;
            wT[(jq*4+3)*192 + o*12 + j] = wv.w;
        }
        __syncthreads();
        const float* rbase = r + (pt*4)*132 + k0;
        #pragma unroll 4
        for (int k = 0; k < 32; k++){
            float4 wa = *(const float4*)(wT + k*192 + ot*12);
            float4 wb = *(const float4*)(wT + k*192 + ot*12 + 4);
            float w8 = wT[k*192 + ot*12 + 8];
            float rv0 = rbase[k];
            float rv1 = rbase[132 + k];
            float rv2 = rbase[264 + k];
            float rv3 = rbase[396 + k];
            float wv[9] = {wa.x, wa.y, wa.z, wa.w, wb.x, wb.y, wb.z, wb.w, w8};
            float rv[4] = {rv0, rv1, rv2, rv3};
            #pragma unroll
            for (int j = 0; j < 9; j++)
                #pragma unroll
                for (int i2 = 0; i2 < 4; i2++)
                    acc[j][i2] = fmaf(wv[j], rv[i2], acc[j][i2]);
        }
    }

    int kd = ot >> 2;
    int cbase = (ot & 3)*9;
    size_t obase = ((size_t)(b*KK + kd))*LL;
    #pragma unroll
    for (int i2 = 0; i2 < 4; i2++){
        int p = ptile*64 + pt*4 + i2;
        int tT = (p & 63)*64 + (p >> 6);
        int t = (kd == 0) ? p : (kd == 1) ? tT : (kd == 2) ? (4095 - p) : (4095 - tT);
        float* dst = xdbl + (obase + t)*XD + cbase;
        #pragma unroll
        for (int j = 0; j < 9; j++) dst[j] = acc[j][i2];
    }
}

// ---------------- K4a: per-chunk local scan -> H, P (128 thr, d/thread, 16 states)
// Fast path exploits An[n] == -(n+1): one exp + 15 muls instead of 16 exps.
__global__ __launch_bounds__(128, 4) void k4a_local(
    const float* __restrict__ xc, const float* __restrict__ xdbl,
    const float* __restrict__ dtw, const float* __restrict__ dtb,
    const float* __restrict__ A_logs,
    float* __restrict__ Pbuf, float* __restrict__ Hbuf)
{
    int bid = blockIdx.x;            // ((b*4+k)*64+cc)
    int cc = bid & 63, k = (bid >> 6) & 3, b = bid >> 8;
    int d = threadIdx.x;
    int kd = k*DI + d;
    float4 wv4 = *(const float4*)(dtw + kd*4);
    float bias = dtb[kd];
    float An[16];
    bool fast = true;
    {
        const float4* al = (const float4*)(A_logs + kd*16);
        #pragma unroll
        for (int i = 0; i < 4; i++){
            float4 a = al[i];
            An[i*4+0] = -__expf(a.x); An[i*4+1] = -__expf(a.y);
            An[i*4+2] = -__expf(a.z); An[i*4+3] = -__expf(a.w);
        }
        #pragma unroll
        for (int n = 0; n < 16; n++)
            fast = fast && (fabsf(An[n] + (float)(n+1)) < 1e-3f*(float)(n+1));
    }
    __shared__ float sraw[TT*XD];
    const float* src = xdbl + ((size_t)(b*KK + k)*LL + cc*TT)*XD;
    for (int i = threadIdx.x; i < TT*XD/4; i += 128)
        ((float4*)sraw)[i] = ((const float4*)src)[i];
    __syncthreads();

    const float* xcb = xc + (size_t)b*LL*DI;
    float h[16];
    #pragma unroll
    for (int i = 0; i < 16; i++) h[i] = 0.f;
    float Sdt = 0.f;

    if (fast){
        for (int t = 0; t < TT; t++){
            const float* rp = sraw + t*XD;
            float4 xr = *(const float4*)rp;
            float dtr = fmaf(xr.x, wv4.x, fmaf(xr.y, wv4.y, fmaf(xr.z, wv4.z, fmaf(xr.w, wv4.w, bias))));
            float dt = softplusf(dtr);
            Sdt += dt;
            int p = p_of(k, cc*TT + t);
            float u = xcb[(size_t)p*DI + d];
            float du = dt * u;
            float4 B0 = *(const float4*)(rp + 4);
            float4 B1 = *(const float4*)(rp + 8);
            float4 B2 = *(const float4*)(rp + 12);
            float4 B3 = *(const float4*)(rp + 16);
            float Bv[16] = {B0.x,B0.y,B0.z,B0.w, B1.x,B1.y,B1.z,B1.w,
                            B2.x,B2.y,B2.z,B2.w, B3.x,B3.y,B3.z,B3.w};
            float e1 = exp2f(-1.44269504f * dt);   // exp(-dt)
            float e = e1;
            h[0] = fmaf(h[0], e, du*Bv[0]);
            #pragma unroll
            for (int i = 1; i < 16; i++){
                e *= e1;                            // e = exp(-(i+1)dt)
                h[i] = fmaf(h[i], e, du*Bv[i]);
            }
        }
        size_t ob = ((size_t)bid)*2048 + d*16;
        float P1 = exp2f(-1.44269504f * Sdt);
        float P = P1;
        Pbuf[ob] = P; Hbuf[ob] = h[0];
        #pragma unroll
        for (int i = 1; i < 16; i++){
            P *= P1;
            Pbuf[ob + i] = P;
            Hbuf[ob + i] = h[i];
        }
    } else {
        float An2[16];
        #pragma unroll
        for (int i = 0; i < 16; i++) An2[i] = An[i] * 1.44269504f;
        for (int t = 0; t < TT; t++){
            const float* rp = sraw + t*XD;
            float4 xr = *(const float4*)rp;
            float dtr = fmaf(xr.x, wv4.x, fmaf(xr.y, wv4.y, fmaf(xr.z, wv4.z, fmaf(xr.w, wv4.w, bias))));
            float dt = softplusf(dtr);
            Sdt += dt;
            int p = p_of(k, cc*TT + t);
            float u = xcb[(size_t)p*DI + d];
            float du = dt * u;
            float4 B0 = *(const float4*)(rp + 4);
            float4 B1 = *(const float4*)(rp + 8);
            float4 B2 = *(const float4*)(rp + 12);
            float4 B3 = *(const float4*)(rp + 16);
            float Bv[16] = {B0.x,B0.y,B0.z,B0.w, B1.x,B1.y,B1.z,B1.w,
                            B2.x,B2.y,B2.z,B2.w, B3.x,B3.y,B3.z,B3.w};
            #pragma unroll
            for (int i = 0; i < 16; i++)
                h[i] = fmaf(h[i], exp2f(dt*An2[i]), du*Bv[i]);
        }
        size_t ob = ((size_t)bid)*2048 + d*16;
        #pragma unroll
        for (int i = 0; i < 16; i++){
            Pbuf[ob + i] = exp2f(An2[i] * Sdt);
            Hbuf[ob + i] = h[i];
        }
    }
}

// ---------------- K4b: chunk-boundary propagation
__global__ __launch_bounds__(256) void k4b_prop(
    const float* __restrict__ Pbuf, const float* __restrict__ Hbuf,
    float* __restrict__ hin_buf)
{
    int chain = blockIdx.x*256 + threadIdx.x;
    int bk = chain >> 11, s = chain & 2047;
    float hin = 0.f;
    for (int c = 0; c < GG; c++){
        size_t idx = ((size_t)(bk*GG + c))*2048 + s;
        hin_buf[idx] = hin;
        hin = fmaf(Pbuf[idx], hin, Hbuf[idx]);
    }
}

// ---------------- K4c: per-chunk re-scan seeded with hin, emit y (128 thr)
__global__ __launch_bounds__(128, 4) void k4c_emit(
    const float* __restrict__ xc, const float* __restrict__ xdbl,
    const float* __restrict__ dtw, const float* __restrict__ dtb,
    const float* __restrict__ A_logs, const float* __restrict__ Ds,
    const float* __restrict__ hin_buf,
    float* __restrict__ y)
{
    int bid = blockIdx.x;
    int cc = bid & 63, k = (bid >> 6) & 3, b = bid >> 8;
    int d = threadIdx.x;
    int kd = k*DI + d;
    float4 wv4 = *(const float4*)(dtw + kd*4);
    float bias = dtb[kd];
    float Dv = Ds[kd];
    float An[16];
    bool fast = true;
    {
        const float4* al = (const float4*)(A_logs + kd*16);
        #pragma unroll
        for (int i = 0; i < 4; i++){
            float4 a = al[i];
            An[i*4+0] = -__expf(a.x); An[i*4+1] = -__expf(a.y);
            An[i*4+2] = -__expf(a.z); An[i*4+3] = -__expf(a.w);
        }
        #pragma unroll
        for (int n = 0; n < 16; n++)
            fast = fast && (fabsf(An[n] + (float)(n+1)) < 1e-3f*(float)(n+1));
    }
    __shared__ float sraw[TT*XD];
    const float* src = xdbl + ((size_t)(b*KK + k)*LL + cc*TT)*XD;
    for (int i = threadIdx.x; i < TT*XD/4; i += 128)
        ((float4*)sraw)[i] = ((const float4*)src)[i];
    __syncthreads();

    const float* xcb = xc + (size_t)b*LL*DI;
    float* yb = y + (size_t)b*LL*DI;
    float h[16];
    {
        const float4* hi = (const float4*)(hin_buf + ((size_t)bid)*2048 + d*16);
        #pragma unroll
        for (int i = 0; i < 4; i++){
            float4 a = hi[i];
            h[i*4+0] = a.x; h[i*4+1] = a.y; h[i*4+2] = a.z; h[i*4+3] = a.w;
        }
    }

    if (fast){
        for (int t = 0; t < TT; t++){
            const float* rp = sraw + t*XD;
            float4 xr = *(const float4*)rp;
            float dtr = fmaf(xr.x, wv4.x, fmaf(xr.y, wv4.y, fmaf(xr.z, wv4.z, fmaf(xr.w, wv4.w, bias))));
            float dt = softplusf(dtr);
            int p = p_of(k, cc*TT + t);
            float u = xcb[(size_t)p*DI + d];
            float du = dt * u;
            float4 B0 = *(const float4*)(rp + 4);
            float4 B1 = *(const float4*)(rp + 8);
            float4 B2 = *(const float4*)(rp + 12);
            float4 B3 = *(const float4*)(rp + 16);
            float Bv[16] = {B0.x,B0.y,B0.z,B0.w, B1.x,B1.y,B1.z,B1.w,
                            B2.x,B2.y,B2.z,B2.w, B3.x,B3.y,B3.z,B3.w};
            float4 C0 = *(const float4*)(rp + 20);
            float4 C1 = *(const float4*)(rp + 24);
            float4 C2 = *(const float4*)(rp + 28);
            float4 C3 = *(const float4*)(rp + 32);
            float Cv[16] = {C0.x,C0.y,C0.z,C0.w, C1.x,C1.y,C1.z,C1.w,
                            C2.x,C2.y,C2.z,C2.w, C3.x,C3.y,C3.z,C3.w};
            float yv = Dv * u;
            float e1 = exp2f(-1.44269504f * dt);
            float e = e1;
            h[0] = fmaf(h[0], e, du*Bv[0]);
            yv = fmaf(h[0], Cv[0], yv);
            #pragma unroll
            for (int i = 1; i < 16; i++){
                e *= e1;
                h[i] = fmaf(h[i], e, du*Bv[i]);
                yv = fmaf(h[i], Cv[i], yv);
            }
            atomicAdd(&yb[(size_t)p*DI + d], yv);
        }
    } else {
        float An2[16];
        #pragma unroll
        for (int i = 0; i < 16; i++) An2[i] = An[i] * 1.44269504f;
        for (int t = 0; t < TT; t++){
            const float* rp = sraw + t*XD;
            float4 xr = *(const float4*)rp;
            float dtr = fmaf(xr.x, wv4.x, fmaf(xr.y, wv4.y, fmaf(xr.z, wv4.z, fmaf(xr.w, wv4.w, bias))));
            float dt = softplusf(dtr);
            int p = p_of(k, cc*TT + t);
            float u = xcb[(size_t)p*DI + d];
            float du = dt * u;
            float4 B0 = *(const float4*)(rp + 4);
            float4 B1 = *(const float4*)(rp + 8);
            float4 B2 = *(const float4*)(rp + 12);
            float4 B3 = *(const float4*)(rp + 16);
            float Bv[16] = {B0.x,B0.y,B0.z,B0.w, B1.x,B1.y,B1.z,B1.w,
                            B2.x,B2.y,B2.z,B2.w, B3.x,B3.y,B3.z,B3.w};
            float4 C0 = *(const float4*)(rp + 20);
            float4 C1 = *(const float4*)(rp + 24);
            float4 C2 = *(const float4*)(rp + 28);
            float4 C3 = *(const float4*)(rp + 32);
            float Cv[16] = {C0.x,C0.y,C0.z,C0.w, C1.x,C1.y,C1.z,C1.w,
                            C2.x,C2.y,C2.z,C2.w, C3.x,C3.y,C3.z,C3.w};
            float yv = Dv * u;
            #pragma unroll
            for (int i = 0; i < 16; i++){
                h[i] = fmaf(h[i], exp2f(dt*An2[i]), du*Bv[i]);
                yv = fmaf(h[i], Cv[i], yv);
            }
            atomicAdd(&yb[(size_t)p*DI + d], yv);
        }
    }
}

// ---------------- K4 serial fallback (used if ws too small)
__global__ __launch_bounds__(256) void k4_scan(
    const float* __restrict__ xc, const float* __restrict__ xdbl,
    const float* __restrict__ dtw, const float* __restrict__ dtb,
    const float* __restrict__ A_logs, const float* __restrict__ Ds,
    float* __restrict__ y)
{
    int bid = blockIdx.x;
    int b = bid >> 5, k = (bid >> 3) & 3, grp = bid & 7;
    int d0 = grp * 16;
    int tid = threadIdx.x;
    int wv = tid >> 6, lane = tid & 63, n = lane & 15, j = lane >> 4;
    int ch = wv*4 + j;
    int d = d0 + ch;
    int kd = k*DI + d;
    float An = -__expf(A_logs[kd*NN + n]);
    int ch_s = tid & 15;
    int kds = k*DI + d0 + ch_s;
    float w0s = dtw[kds*4+0], w1s = dtw[kds*4+1], w2s = dtw[kds*4+2], w3s = dtw[kds*4+3];
    float bs  = dtb[kds];
    float Dvs = Ds[kds];
    __shared__ float sraw[64*XD];
    __shared__ float sdd[64*16*2];
    __shared__ float sdy[64*17];
    const float* xdbase = xdbl + (size_t)(b*KK + k)*LL*XD;
    const float* xcb = xc + (size_t)b*LL*DI;
    float* yb = y + (size_t)b*LL*DI;
    float h = 0.f;
    for (int cc = 0; cc < 64; cc++){
        __syncthreads();
        const float* src = xdbase + (size_t)cc*64*XD;
        for (int i2 = tid; i2 < 576; i2 += 256)
            ((float4*)sraw)[i2] = ((const float4*)src)[i2];
        #pragma unroll
        for (int it = 0; it < 4; it++){
            int idx = tid + it*256;
            int t = idx >> 4;
            int pu = p_of(k, cc*64 + t);
            float u = xcb[(size_t)pu*DI + d0 + ch_s];
            float4 xr = *(const float4*)(src + t*XD);
            float dtr = fmaf(xr.x, w0s, fmaf(xr.y, w1s, fmaf(xr.z, w2s, fmaf(xr.w, w3s, bs))));
            float dt = softplusf(dtr);
            sdd[idx*2]     = dt;
            sdd[idx*2 + 1] = dt*u;
            sdy[t*17 + ch_s] = Dvs * u;
        }
        __syncthreads();
        #pragma unroll
        for (int tg = 0; tg < 4; tg++){
            float myv = 0.f;
            #pragma unroll
            for (int it = 0; it < 16; it++){
                int t = tg*16 + it;
                float dt = sdd[(t*16 + ch)*2];
                float du = sdd[(t*16 + ch)*2 + 1];
                float Bn = sraw[t*XD + 4 + n];
                float Cn = sraw[t*XD + 20 + n];
                float e = __expf(dt * An);
                h = fmaf(h, e, du * Bn);
                float yv = h * Cn;
                yv = dpp_xadd<0xB1>(yv);
                yv = dpp_xadd<0x4E>(yv);
                yv = dpp_xadd<0x141>(yv);
                yv = dpp_xadd<0x140>(yv);
                if (it == n) myv = yv;
            }
            int t = tg*16 + n;
            float yt = myv + sdy[t*17 + ch];
            int p = p_of(k, cc*64 + t);
            atomicAdd(&yb[(size_t)p*DI + d], yt);
        }
    }
}

// ---------------- K5: LN(DI)*silu(z) + out_proj + residual + fused channel-LN
__global__ __launch_bounds__(256) void k5_out(
    const float* __restrict__ y, const float* __restrict__ zs,
    const float* __restrict__ on_g, const float* __restrict__ on_b,
    const float* __restrict__ opw,  // (64,128)
    const float* __restrict__ opb,
    const float* __restrict__ x,    // (B,C,L)
    const float* __restrict__ cn_g, const float* __restrict__ cn_b,
    float* __restrict__ xo, float* __restrict__ cl)
{
    int bid = blockIdx.x;
    int b = bid >> 6, p0 = (bid & 63)*64;
    int tid = threadIdx.x;

    __shared__ float vT[128*68];
    __shared__ float wT[128*68];
    __shared__ float gb[256];
    __shared__ float ob[64];
    __shared__ float cgb[128];
    __shared__ float red[2048];
    __shared__ float mv[128];

    gb[tid] = (tid < 128) ? on_g[tid] : on_b[tid - 128];
    if (tid < 64) ob[tid] = opb[tid];
    if (tid >= 128 && tid < 256) cgb[tid-128] = (tid < 192) ? cn_g[tid-128] : cn_b[tid-192];

    #pragma unroll
    for (int it = 0; it < 8; it++){
        int i = tid + it*256;
        int c = i >> 5, jq = i & 31;
        float4 wv = *(const float4*)(opw + c*128 + jq*4);
        wT[(jq*4+0)*68 + c] = wv.x;
        wT[(jq*4+1)*68 + c] = wv.y;
        wT[(jq*4+2)*68 + c] = wv.z;
        wT[(jq*4+3)*68 + c] = wv.w;
    }

    int pix = tid >> 2, q = tid & 3;
    size_t base = ((size_t)(b*LL) + p0 + pix)*DI + q*32;
    float yv[32];
    {
        const float4* y4 = (const float4*)(y + base);
        float s = 0.f, sq = 0.f;
        #pragma unroll
        for (int i = 0; i < 8; i++){
            float4 a = y4[i];
            yv[i*4+0] = a.x; yv[i*4+1] = a.y; yv[i*4+2] = a.z; yv[i*4+3] = a.w;
            s += a.x + a.y + a.z + a.w;
            sq = fmaf(a.x,a.x, fmaf(a.y,a.y, fmaf(a.z,a.z, fmaf(a.w,a.w, sq))));
        }
        red[tid*2] = s; red[tid*2+1] = sq;
    }
    __syncthreads();
    if (tid < 64){
        float s = red[tid*8] + red[tid*8+2] + red[tid*8+4] + red[tid*8+6];
        float sq = red[tid*8+1] + red[tid*8+3] + red[tid*8+5] + red[tid*8+7];
        float mean = s * (1.f/128.f);
        float var  = sq * (1.f/128.f) - mean*mean;
        mv[tid*2] = mean; mv[tid*2+1] = rsqrtf(var + 1e-5f);
    }
    __syncthreads();
    {
        float mean = mv[pix*2], rstd = mv[pix*2+1];
        const float4* z4 = (const float4*)(zs + base);
        #pragma unroll
        for (int i = 0; i < 8; i++){
            float4 zz = z4[i];
            float zv[4] = {zz.x, zz.y, zz.z, zz.w};
            #pragma unroll
            for (int jj = 0; jj < 4; jj++){
                int dd = q*32 + i*4 + jj;
                float vn = (yv[i*4+jj] - mean)*rstd*gb[dd] + gb[128+dd];
                vT[dd*68 + pix] = vn * zv[jj];
            }
        }
    }
    __syncthreads();

    int pt = tid >> 4, ot = tid & 15;
    float acc[4][4];
    #pragma unroll
    for (int j = 0; j < 4; j++)
        #pragma unroll
        for (int i2 = 0; i2 < 4; i2++) acc[j][i2] = 0.f;

    #pragma unroll 4
    for (int k = 0; k < 128; k++){
        float4 rv = *(const float4*)(vT + k*68 + pt*4);
        float4 wv = *(const float4*)(wT + k*68 + ot*4);
        acc[0][0] = fmaf(wv.x, rv.x, acc[0][0]); acc[0][1] = fmaf(wv.x, rv.y, acc[0][1]);
        acc[0][2] = fmaf(wv.x, rv.z, acc[0][2]); acc[0][3] = fmaf(wv.x, rv.w, acc[0][3]);
        acc[1][0] = fmaf(wv.y, rv.x, acc[1][0]); acc[1][1] = fmaf(wv.y, rv.y, acc[1][1]);
        acc[1][2] = fmaf(wv.y, rv.z, acc[1][2]); acc[1][3] = fmaf(wv.y, rv.w, acc[1][3]);
        acc[2][0] = fmaf(wv.z, rv.x, acc[2][0]); acc[2][1] = fmaf(wv.z, rv.y, acc[2][1]);
        acc[2][2] = fmaf(wv.z, rv.z, acc[2][2]); acc[2][3] = fmaf(wv.z, rv.w, acc[2][3]);
        acc[3][0] = fmaf(wv.w, rv.x, acc[3][0]); acc[3][1] = fmaf(wv.w, rv.y, acc[3][1]);
        acc[3][2] = fmaf(wv.w, rv.z, acc[3][2]); acc[3][3] = fmaf(wv.w, rv.w, acc[3][3]);
    }

    #pragma unroll
    for (int jj = 0; jj < 4; jj++){
        int c = ot*4 + jj;
        float4 xr = *(const float4*)(x + ((size_t)(b*CC + c))*LL + p0 + pt*4);
        acc[jj][0] += ob[c] + xr.x;
        acc[jj][1] += ob[c] + xr.y;
        acc[jj][2] += ob[c] + xr.z;
        acc[jj][3] += ob[c] + xr.w;
    }
    #pragma unroll
    for (int i2 = 0; i2 < 4; i2++){
        float4 v = make_float4(acc[0][i2], acc[1][i2], acc[2][i2], acc[3][i2]);
        *(float4*)(xo + ((size_t)(b*LL) + p0 + pt*4 + i2)*CC + ot*4) = v;
    }

    __syncthreads();
    #pragma unroll
    for (int i2 = 0; i2 < 4; i2++){
        float s = acc[0][i2] + acc[1][i2] + acc[2][i2] + acc[3][i2];
        float sq = fmaf(acc[0][i2],acc[0][i2], fmaf(acc[1][i2],acc[1][i2],
                   fmaf(acc[2][i2],acc[2][i2], acc[3][i2]*acc[3][i2])));
        red[(pt*4 + i2)*16 + ot] = s;
        red[1024 + (pt*4 + i2)*16 + ot] = sq;
    }
    __syncthreads();
    if (tid < 64){
        float s = 0.f, sq = 0.f;
        #pragma unroll
        for (int o = 0; o < 16; o++){
            s += red[tid*16 + o];
            sq += red[1024 + tid*16 + o];
        }
        float mean = s * (1.f/64.f);
        float var  = sq * (1.f/64.f) - mean*mean;
        mv[tid*2] = mean; mv[tid*2+1] = rsqrtf(var + 1e-6f);
    }
    __syncthreads();
    #pragma unroll
    for (int i2 = 0; i2 < 4; i2++){
        float mean = mv[(pt*4+i2)*2], rstd = mv[(pt*4+i2)*2+1];
        float4 v;
        v.x = (acc[0][i2] - mean)*rstd*cgb[ot*4+0] + cgb[64+ot*4+0];
        v.y = (acc[1][i2] - mean)*rstd*cgb[ot*4+1] + cgb[64+ot*4+1];
        v.z = (acc[2][i2] - mean)*rstd*cgb[ot*4+2] + cgb[64+ot*4+2];
        v.w = (acc[3][i2] - mean)*rstd*cgb[ot*4+3] + cgb[64+ot*4+3];
        *(float4*)(cl + ((size_t)(b*LL) + p0 + pt*4 + i2)*CC + ot*4) = v;
    }
}

// ---------------- K7: max pools 2/4/8 for SAFM branches 1..3
__global__ __launch_bounds__(256) void k7_pools(const float* __restrict__ cl, float* __restrict__ pools)
{
    int idx = blockIdx.x*256 + threadIdx.x;
    int g, S, base;
    if (idx < 131072)      { g = 1; S = 32; base = 0; }
    else if (idx < 163840) { g = 2; S = 16; base = 131072; idx -= 131072; }
    else if (idx < 172032) { g = 3; S = 8;  base = 163840; idx -= 163840; }
    else return;
    int pw = idx % S; idx /= S;
    int ph = idx % S; idx /= S;
    int j = idx & 15; int b = idx >> 4;
    int kk = 64 / S;
    int c = g*16 + j;
    float m = -1e30f;
    for (int dy = 0; dy < kk; dy++)
        for (int dx = 0; dx < kk; dx++){
            int h = ph*kk + dy, w = pw*kk + dx;
            m = fmaxf(m, cl[((size_t)(b*LL) + h*64 + w)*CC + c]);
        }
    pools[base + ((size_t)(b*16 + j)*S + ph)*S + pw] = m;
}

// ---------------- K8: SAFM branch depthwise convs -> cat (B,L,C)
__global__ __launch_bounds__(256) void k8_mfr(
    const float* __restrict__ cl, const float* __restrict__ pools,
    const float* __restrict__ mfr_w,  // (4,16,3,3)
    const float* __restrict__ mfr_b,  // (4,16)
    float* __restrict__ cat)
{
    int idx = blockIdx.x*256 + threadIdx.x;
    int c = idx & 63; int bp = idx >> 6;
    int p = bp & 4095, b = bp >> 12;
    int g = c >> 4, j = c & 15;
    int h = p >> 6, w = p & 63;
    float acc = mfr_b[g*16 + j];
    const float* wr = mfr_w + (g*16 + j)*9;
    if (g == 0){
        #pragma unroll
        for (int ky = 0; ky < 3; ky++){
            int hh = h + ky - 1; if ((unsigned)hh >= 64u) continue;
            #pragma unroll
            for (int kx = 0; kx < 3; kx++){
                int ww = w + kx - 1; if ((unsigned)ww >= 64u) continue;
                acc = fmaf(cl[((size_t)(b*LL) + hh*64 + ww)*CC + c], wr[ky*3 + kx], acc);
            }
        }
    } else {
        int S = 64 >> g;
        int ph = h >> g, pw = w >> g;
        int base = (g == 1) ? 0 : ((g == 2) ? 131072 : 163840);
        const float* P = pools + base + (size_t)(b*16 + j)*S*S;
        #pragma unroll
        for (int ky = 0; ky < 3; ky++){
            int hh = ph + ky - 1; if ((unsigned)hh >= (unsigned)S) continue;
            #pragma unroll
            for (int kx = 0; kx < 3; kx++){
                int ww = pw + kx - 1; if ((unsigned)ww >= (unsigned)S) continue;
                acc = fmaf(P[hh*S + ww], wr[ky*3 + kx], acc);
            }
        }
    }
    cat[idx] = acc;
}

// ---------------- K9: 1x1 agg + GELU*cl + residual, tiled GEMM -> out (B,C,L)
__global__ __launch_bounds__(256) void k9_agg(
    const float* __restrict__ cat, const float* __restrict__ cl, const float* __restrict__ xo,
    const float* __restrict__ agw,   // (64,64)
    const float* __restrict__ agb,
    float* __restrict__ out)
{
    int bid = blockIdx.x;
    int b = bid >> 6, p0 = (bid & 63)*64;
    int tid = threadIdx.x;

    __shared__ float catT[64*68];
    __shared__ float wT[64*68];
    __shared__ float ab[64];

    if (tid < 64) ab[tid] = agb[tid];
    #pragma unroll
    for (int it = 0; it < 4; it++){
        int i = tid + it*256;
        int pix = i >> 4, cq = i & 15;
        float4 v = *(const float4*)(cat + ((size_t)(b*LL) + p0 + pix)*CC + cq*4);
        catT[(cq*4+0)*68 + pix] = v.x;
        catT[(cq*4+1)*68 + pix] = v.y;
        catT[(cq*4+2)*68 + pix] = v.z;
        catT[(cq*4+3)*68 + pix] = v.w;
        int o = i >> 4;
        float4 wv = *(const float4*)(agw + o*64 + cq*4);
        wT[(cq*4+0)*68 + o] = wv.x;
        wT[(cq*4+1)*68 + o] = wv.y;
        wT[(cq*4+2)*68 + o] = wv.z;
        wT[(cq*4+3)*68 + o] = wv.w;
    }
    __syncthreads();

    int pt = tid >> 4, ot = tid & 15;
    float acc[4][4];
    #pragma unroll
    for (int j = 0; j < 4; j++)
        #pragma unroll
        for (int i2 = 0; i2 < 4; i2++) acc[j][i2] = 0.f;

    #pragma unroll 4
    for (int k = 0; k < 64; k++){
        float4 rv = *(const float4*)(catT + k*68 + pt*4);
        float4 wv = *(const float4*)(wT + k*68 + ot*4);
        acc[0][0] = fmaf(wv.x, rv.x, acc[0][0]); acc[0][1] = fmaf(wv.x, rv.y, acc[0][1]);
        acc[0][2] = fmaf(wv.x, rv.z, acc[0][2]); acc[0][3] = fmaf(wv.x, rv.w, acc[0][3]);
        acc[1][0] = fmaf(wv.y, rv.x, acc[1][0]); acc[1][1] = fmaf(wv.y, rv.y, acc[1][1]);
        acc[1][2] = fmaf(wv.y, rv.z, acc[1][2]); acc[1][3] = fmaf(wv.y, rv.w, acc[1][3]);
        acc[2][0] = fmaf(wv.z, rv.x, acc[2][0]); acc[2][1] = fmaf(wv.z, rv.y, acc[2][1]);
        acc[2][2] = fmaf(wv.z, rv.z, acc[2][2]); acc[2][3] = fmaf(wv.z, rv.w, acc[2][3]);
        acc[3][0] = fmaf(wv.w, rv.x, acc[3][0]); acc[3][1] = fmaf(wv.w, rv.y, acc[3][1]);
        acc[3][2] = fmaf(wv.w, rv.z, acc[3][2]); acc[3][3] = fmaf(wv.w, rv.w, acc[3][3]);
    }

    float res[4][4];
    #pragma unroll
    for (int i2 = 0; i2 < 4; i2++){
        size_t prow = ((size_t)(b*LL) + p0 + pt*4 + i2)*CC + ot*4;
        float4 clv = *(const float4*)(cl + prow);
        float4 xov = *(const float4*)(xo + prow);
        float cla[4] = {clv.x, clv.y, clv.z, clv.w};
        float xoa[4] = {xov.x, xov.y, xov.z, xov.w};
        #pragma unroll
        for (int jj = 0; jj < 4; jj++){
            float av = acc[jj][i2] + ab[ot*4 + jj];
            float gl = 0.5f*av*(1.f + erff(av*0.70710678118f));
            res[jj][i2] = xoa[jj] + gl*cla[jj];
        }
    }
    #pragma unroll
    for (int jj = 0; jj < 4; jj++){
        int o = ot*4 + jj;
        float4 v = make_float4(res[jj][0], res[jj][1], res[jj][2], res[jj][3]);
        *(float4*)(out + ((size_t)(b*CC + o))*LL + p0 + pt*4) = v;
    }
}

extern "C" void kernel_launch(void* const* d_in, const int* in_sizes, int n_in,
                              void* d_out, int out_size, void* d_ws, size_t ws_size,
                              hipStream_t stream)
{
    const float* x       = (const float*)d_in[0];
    const float* ln1_g   = (const float*)d_in[1];
    const float* ln1_b   = (const float*)d_in[2];
    const float* ipw     = (const float*)d_in[3];
    const float* ipb     = (const float*)d_in[4];
    const float* conv_w  = (const float*)d_in[5];
    const float* conv_b  = (const float*)d_in[6];
    const float* xpw     = (const float*)d_in[7];
    const float* dtw     = (const float*)d_in[8];
    const float* dtb     = (const float*)d_in[9];
    const float* A_logs  = (const float*)d_in[10];
    const float* Ds      = (const float*)d_in[11];
    const float* on_g    = (const float*)d_in[12];
    const float* on_b    = (const float*)d_in[13];
    const float* opw     = (const float*)d_in[14];
    const float* opb     = (const float*)d_in[15];
    const float* mfr_w   = (const float*)d_in[16];
    const float* mfr_b   = (const float*)d_in[17];
    const float* agw     = (const float*)d_in[18];
    const float* agb     = (const float*)d_in[19];
    const float* cn_g    = (const float*)d_in[20];
    const float* cn_b    = (const float*)d_in[21];
    float* out = (float*)d_out;

    float* ws = (float*)d_ws;
    float* xi    = ws;               // reused as y
    float* zs    = ws + 4194304;     // reused as cat
    float* xc    = ws + 8388608;     // reused as xo + pools
    float* xdbl  = ws + 12582912;    // reused as cl
    float* y     = xi;
    float* xo    = xc;
    float* pools = xc + 2097152;
    float* cl    = xdbl;
    float* cat   = zs;
    float* Pbuf  = ws + 17301504;
    float* Hbuf  = ws + 21495808;
    float* hinb  = ws + 25690112;
    bool par = ws_size >= (size_t)29884416 * 4;

    // SS2D
    hipLaunchKernelGGL(k1_ln_inproj, dim3(BB*64), dim3(256), 0, stream,
                       x, ln1_g, ln1_b, ipw, ipb, xi, zs);
    hipLaunchKernelGGL(k2_dwconv, dim3(BB*LL*DI/1024), dim3(256), 0, stream,
                       xi, conv_w, conv_b, xc);
    hipLaunchKernelGGL(k3_xdbl, dim3(BB*64), dim3(256), 0, stream,
                       xc, xpw, xdbl);
    hipMemsetAsync(y, 0, (size_t)BB*LL*DI*sizeof(float), stream);
    if (par){
        hipLaunchKernelGGL(k4a_local, dim3(BB*KK*GG), dim3(128), 0, stream,
                           xc, xdbl, dtw, dtb, A_logs, Pbuf, Hbuf);
        hipLaunchKernelGGL(k4b_prop, dim3(256), dim3(256), 0, stream,
                           Pbuf, Hbuf, hinb);
        hipLaunchKernelGGL(k4c_emit, dim3(BB*KK*GG), dim3(128), 0, stream,
                           xc, xdbl, dtw, dtb, A_logs, Ds, hinb, y);
    } else {
        hipLaunchKernelGGL(k4_scan, dim3(256), dim3(256), 0, stream,
                           xc, xdbl, dtw, dtb, A_logs, Ds, y);
    }
    hipLaunchKernelGGL(k5_out, dim3(BB*64), dim3(256), 0, stream,
                       y, zs, on_g, on_b, opw, opb, x, cn_g, cn_b, xo, cl);
    // SAFM (k6 fused into k5)
    hipLaunchKernelGGL(k7_pools, dim3((172032 + 255)/256), dim3(256), 0, stream,
                       cl, pools);
    hipLaunchKernelGGL(k8_mfr, dim3(BB*LL*CC/256), dim3(256), 0, stream,
                       cl, pools, mfr_w, mfr_b, cat);
    hipLaunchKernelGGL(k9_agg, dim3(BB*64), dim3(256), 0, stream,
                       cat, cl, xo, agw, agb, out);
}

// Round 9
// 351.698 us; speedup vs baseline: 1.2789x; 1.0325x over previous
//
#include <hip/hip_runtime.h>
#include <hip/hip_bf16.h>

#define BB 8
#define CC 64
#define HH 64
#define WW 64
#define LL 4096
#define DI 128
#define KK 4
#define NN 16
#define RR 4
#define XD 36   // R + 2N
#define GG 64   // scan chunks
#define TT 64   // timesteps per chunk

__device__ __forceinline__ float softplusf(float x){
    return fmaxf(x, 0.f) + __logf(1.f + __expf(-fabsf(x)));
}
__device__ __forceinline__ int p_of(int k, int t){
    int tt = (k & 2) ? (LL - 1 - t) : t;
    return (k & 1) ? ((tt & 63) * 64 + (tt >> 6)) : tt;
}
// 16 powers of e1 with dependency depth 4 (binary squaring)
__device__ __forceinline__ void pow16(float e1, float* E){
    float e2 = e1*e1;
    float e4 = e2*e2;
    float e8 = e4*e4;
    E[0]=e1;    E[1]=e2;    E[2]=e2*e1;  E[3]=e4;
    E[4]=e4*e1; E[5]=e4*e2; E[6]=e4*E[2];E[7]=e8;
    E[8]=e8*e1; E[9]=e8*e2; E[10]=e8*E[2]; E[11]=e8*e4;
    E[12]=e8*E[4]; E[13]=e8*E[5]; E[14]=e8*E[6]; E[15]=e8*e8;
}

// DPP butterfly add (serial fallback kernel only)
template<int CTRL>
__device__ __forceinline__ float dpp_xadd(float v){
    int t = __builtin_amdgcn_update_dpp(0, __float_as_int(v), CTRL, 0xF, 0xF, true);
    return v + __int_as_float(t);
}

// ---------------- K1: LN(C) + in_proj, 64-pixel-tile LDS GEMM
__global__ __launch_bounds__(256) void k1_ln_inproj(
    const float* __restrict__ x,     // (B,C,L)
    const float* __restrict__ ln1_g,
    const float* __restrict__ ln1_b,
    const float* __restrict__ ipw,   // (256,64)
    const float* __restrict__ ipb,   // (256)
    float* __restrict__ xi, float* __restrict__ zs)
{
    int bid = blockIdx.x;            // b*64 + ptile
    int b = bid >> 6, p0 = (bid & 63)*64;
    int tid = threadIdx.x;

    __shared__ float xs[64*65];      // xs[pix][c]
    __shared__ float lnxT[64*68];    // lnxT[c][pix]
    __shared__ float wT[16*260];     // chunk weights wT[k][d]
    __shared__ float gb[128];
    __shared__ float bias[256];
    __shared__ float red[512];
    __shared__ float mv[128];

    if (tid < 128) gb[tid] = (tid < 64) ? ln1_g[tid] : ln1_b[tid - 64];
    bias[tid] = ipb[tid];

    #pragma unroll
    for (int it = 0; it < 4; it++){
        int i = tid + it*256;        // 1024 float4
        int c = i >> 4, pq = i & 15;
        float4 v = *(const float4*)(x + ((size_t)(b*CC + c))*LL + p0 + pq*4);
        xs[(pq*4+0)*65 + c] = v.x;
        xs[(pq*4+1)*65 + c] = v.y;
        xs[(pq*4+2)*65 + c] = v.z;
        xs[(pq*4+3)*65 + c] = v.w;
    }
    __syncthreads();

    {
        int pix = tid >> 2, q = tid & 3;
        float s = 0.f, sq = 0.f;
        #pragma unroll
        for (int cc = 0; cc < 16; cc++){
            float v = xs[pix*65 + q*16 + cc];
            s += v; sq = fmaf(v, v, sq);
        }
        red[tid*2] = s; red[tid*2+1] = sq;
    }
    __syncthreads();
    if (tid < 64){
        float s = red[tid*8] + red[tid*8+2] + red[tid*8+4] + red[tid*8+6];
        float sq = red[tid*8+1] + red[tid*8+3] + red[tid*8+5] + red[tid*8+7];
        float mean = s * (1.f/64.f);
        float var  = sq * (1.f/64.f) - mean*mean;
        mv[tid*2] = mean; mv[tid*2+1] = rsqrtf(var + 1e-5f);
    }
    __syncthreads();
    {
        int pix = tid >> 2, q = tid & 3;
        float mean = mv[pix*2], rstd = mv[pix*2+1];
        #pragma unroll
        for (int cc = 0; cc < 16; cc++){
            int c = q*16 + cc;
            float v = (xs[pix*65 + c] - mean)*rstd*gb[c] + gb[64+c];
            lnxT[c*68 + pix] = v;
        }
    }

    int pt = tid >> 4, ot = tid & 15;
    float acc[16][4];
    #pragma unroll
    for (int j = 0; j < 16; j++)
        #pragma unroll
        for (int i2 = 0; i2 < 4; i2++) acc[j][i2] = 0.f;

    for (int kc = 0; kc < 4; kc++){
        __syncthreads();
        #pragma unroll
        for (int it = 0; it < 4; it++){
            int i = tid + it*256;
            int d = i >> 2, jq = i & 3;
            float4 wv = *(const float4*)(ipw + d*64 + kc*16 + jq*4);
            wT[(jq*4+0)*260 + d] = wv.x;
            wT[(jq*4+1)*260 + d] = wv.y;
            wT[(jq*4+2)*260 + d] = wv.z;
            wT[(jq*4+3)*260 + d] = wv.w;
        }
        __syncthreads();
        #pragma unroll
        for (int k = 0; k < 16; k++){
            float4 rv = *(const float4*)(lnxT + (kc*16 + k)*68 + pt*4);
            #pragma unroll
            for (int g = 0; g < 4; g++){
                float4 wv = *(const float4*)(wT + k*260 + g*64 + ot*4);
                acc[g*4+0][0] = fmaf(wv.x, rv.x, acc[g*4+0][0]);
                acc[g*4+0][1] = fmaf(wv.x, rv.y, acc[g*4+0][1]);
                acc[g*4+0][2] = fmaf(wv.x, rv.z, acc[g*4+0][2]);
                acc[g*4+0][3] = fmaf(wv.x, rv.w, acc[g*4+0][3]);
                acc[g*4+1][0] = fmaf(wv.y, rv.x, acc[g*4+1][0]);
                acc[g*4+1][1] = fmaf(wv.y, rv.y, acc[g*4+1][1]);
                acc[g*4+1][2] = fmaf(wv.y, rv.z, acc[g*4+1][2]);
                acc[g*4+1][3] = fmaf(wv.y, rv.w, acc[g*4+1][3]);
                acc[g*4+2][0] = fmaf(wv.z, rv.x, acc[g*4+2][0]);
                acc[g*4+2][1] = fmaf(wv.z, rv.y, acc[g*4+2][1]);
                acc[g*4+2][2] = fmaf(wv.z, rv.z, acc[g*4+2][2]);
                acc[g*4+2][3] = fmaf(wv.z, rv.w, acc[g*4+2][3]);
                acc[g*4+3][0] = fmaf(wv.w, rv.x, acc[g*4+3][0]);
                acc[g*4+3][1] = fmaf(wv.w, rv.y, acc[g*4+3][1]);
                acc[g*4+3][2] = fmaf(wv.w, rv.z, acc[g*4+3][2]);
                acc[g*4+3][3] = fmaf(wv.w, rv.w, acc[g*4+3][3]);
            }
        }
    }

    #pragma unroll
    for (int i2 = 0; i2 < 4; i2++){
        size_t prow = ((size_t)(b*LL) + p0 + pt*4 + i2);
        #pragma unroll
        for (int g = 0; g < 4; g++){
            int dbase = g*64 + ot*4;
            float4 v;
            v.x = acc[g*4+0][i2] + bias[dbase+0];
            v.y = acc[g*4+1][i2] + bias[dbase+1];
            v.z = acc[g*4+2][i2] + bias[dbase+2];
            v.w = acc[g*4+3][i2] + bias[dbase+3];
            if (g < 2){
                *(float4*)(xi + prow*DI + dbase) = v;
            } else {
                v.x = v.x / (1.f + __expf(-v.x));
                v.y = v.y / (1.f + __expf(-v.y));
                v.z = v.z / (1.f + __expf(-v.z));
                v.w = v.w / (1.f + __expf(-v.w));
                *(float4*)(zs + prow*DI + dbase - 128) = v;
            }
        }
    }
}

// ---------------- K2: depthwise 3x3 + SiLU, 4 pixels/thread
__global__ __launch_bounds__(256) void k2_dwconv(
    const float* __restrict__ xi,
    const float* __restrict__ cw,   // (128,3,3)
    const float* __restrict__ cb,
    float* __restrict__ xc)
{
    int idx = blockIdx.x*256 + threadIdx.x;
    int d = idx & 127;
    int g = idx >> 7;
    int p0 = (g & 1023) * 4;
    int b = g >> 10;
    int h = p0 >> 6, w0 = p0 & 63;
    float wt[9];
    #pragma unroll
    for (int j = 0; j < 9; j++) wt[j] = cw[d*9 + j];
    float bv = cb[d];
    float acc[4] = {bv, bv, bv, bv};
    #pragma unroll
    for (int ky = 0; ky < 3; ky++){
        int hh = h + ky - 1;
        if ((unsigned)hh >= 64u) continue;
        const float* row = xi + ((size_t)(b*LL) + hh*64)*DI + d;
        float v0 = (w0 > 0)  ? row[(w0-1)*DI] : 0.f;
        float v1 = row[(w0+0)*DI];
        float v2 = row[(w0+1)*DI];
        float v3 = row[(w0+2)*DI];
        float v4 = row[(w0+3)*DI];
        float v5 = (w0 < 60) ? row[(w0+4)*DI] : 0.f;
        float wa = wt[ky*3], wbv = wt[ky*3+1], wc = wt[ky*3+2];
        acc[0] = fmaf(v0, wa, fmaf(v1, wbv, fmaf(v2, wc, acc[0])));
        acc[1] = fmaf(v1, wa, fmaf(v2, wbv, fmaf(v3, wc, acc[1])));
        acc[2] = fmaf(v2, wa, fmaf(v3, wbv, fmaf(v4, wc, acc[2])));
        acc[3] = fmaf(v3, wa, fmaf(v4, wbv, fmaf(v5, wc, acc[3])));
    }
    #pragma unroll
    for (int i = 0; i < 4; i++){
        float a = acc[i];
        float sg = 1.f / (1.f + __expf(-a));
        xc[((size_t)(b*LL) + p0 + i)*DI + d] = a * sg;
    }
}

// ---------------- K3: x_dbl = xproj(xc), register-tiled LDS GEMM
__global__ __launch_bounds__(256) void k3_xdbl(
    const float* __restrict__ xc,
    const float* __restrict__ xpw,   // (144,128)
    float* __restrict__ xdbl)
{
    int bid = blockIdx.x;
    int b = bid >> 6, ptile = bid & 63;
    int tid = threadIdx.x;
    int ot = tid & 15;
    int pt = tid >> 4;

    __shared__ float r[64*132];
    __shared__ float wT[32*192];

    const float* xcb = xc + ((size_t)(b*LL) + ptile*64)*DI;
    for (int i = tid; i < 2048; i += 256){
        int pix = i >> 5, kq = i & 31;
        float4 v = *(const float4*)(xcb + pix*128 + kq*4);
        *(float4*)(r + pix*132 + kq*4) = v;
    }

    float acc[9][4];
    #pragma unroll
    for (int j = 0; j < 9; j++)
        #pragma unroll
        for (int i2 = 0; i2 < 4; i2++) acc[j][i2] = 0.f;

    for (int kc = 0; kc < 4; kc++){
        __syncthreads();
        int k0 = kc*32;
        for (int i = tid; i < 1152; i += 256){
            int cl = i >> 3, jq = i & 7;
            float4 wv = *(const float4*)(xpw + cl*128 + k0 + jq*4);
            int o = (cl*456) >> 12;
            int j = cl - o*9;
            wT[(jq*4+0)*192 + o*12 + j] = wv.x;
            wT[(jq*4+1)*192 + o*12 + j] = wv.y;
            wT[(jq*4+2)*192 + o*12 + j] = wv.z;
            wT[(jq*4+3)*192 + o*12 + j] = wv.w;
        }
        __syncthreads();
        const float* rbase = r + (pt*4)*132 + k0;
        #pragma unroll 4
        for (int k = 0; k < 32; k++){
            float4 wa = *(const float4*)(wT + k*192 + ot*12);
            float4 wb = *(const float4*)(wT + k*192 + ot*12 + 4);
            float w8 = wT[k*192 + ot*12 + 8];
            float rv0 = rbase[k];
            float rv1 = rbase[132 + k];
            float rv2 = rbase[264 + k];
            float rv3 = rbase[396 + k];
            float wv[9] = {wa.x, wa.y, wa.z, wa.w, wb.x, wb.y, wb.z, wb.w, w8};
            float rv[4] = {rv0, rv1, rv2, rv3};
            #pragma unroll
            for (int j = 0; j < 9; j++)
                #pragma unroll
                for (int i2 = 0; i2 < 4; i2++)
                    acc[j][i2] = fmaf(wv[j], rv[i2], acc[j][i2]);
        }
    }

    int kd = ot >> 2;
    int cbase = (ot & 3)*9;
    size_t obase = ((size_t)(b*KK + kd))*LL;
    #pragma unroll
    for (int i2 = 0; i2 < 4; i2++){
        int p = ptile*64 + pt*4 + i2;
        int tT = (p & 63)*64 + (p >> 6);
        int t = (kd == 0) ? p : (kd == 1) ? tT : (kd == 2) ? (4095 - p) : (4095 - tT);
        float* dst = xdbl + (obase + t)*XD + cbase;
        #pragma unroll
        for (int j = 0; j < 9; j++) dst[j] = acc[j][i2];
    }
}

// ---------------- K4a: per-chunk local scan -> H, P
__global__ __launch_bounds__(128, 4) void k4a_local(
    const float* __restrict__ xc, const float* __restrict__ xdbl,
    const float* __restrict__ dtw, const float* __restrict__ dtb,
    const float* __restrict__ A_logs,
    float* __restrict__ Pbuf, float* __restrict__ Hbuf)
{
    int bid = blockIdx.x;            // ((b*4+k)*64+cc)
    int cc = bid & 63, k = (bid >> 6) & 3, b = bid >> 8;
    int d = threadIdx.x;
    int kd = k*DI + d;
    float4 wv4 = *(const float4*)(dtw + kd*4);
    float bias = dtb[kd];
    float An[16];
    bool fast = true;
    {
        const float4* al = (const float4*)(A_logs + kd*16);
        #pragma unroll
        for (int i = 0; i < 4; i++){
            float4 a = al[i];
            An[i*4+0] = -__expf(a.x); An[i*4+1] = -__expf(a.y);
            An[i*4+2] = -__expf(a.z); An[i*4+3] = -__expf(a.w);
        }
        #pragma unroll
        for (int n = 0; n < 16; n++)
            fast = fast && (fabsf(An[n] + (float)(n+1)) < 1e-3f*(float)(n+1));
    }
    __shared__ float sraw[TT*XD];
    const float* src = xdbl + ((size_t)(b*KK + k)*LL + cc*TT)*XD;
    for (int i = threadIdx.x; i < TT*XD/4; i += 128)
        ((float4*)sraw)[i] = ((const float4*)src)[i];
    __syncthreads();

    const float* xcb = xc + (size_t)b*LL*DI;
    float h[16];
    #pragma unroll
    for (int i = 0; i < 16; i++) h[i] = 0.f;
    float Sdt = 0.f;

    if (fast){
        for (int t = 0; t < TT; t++){
            const float* rp = sraw + t*XD;
            float4 xr = *(const float4*)rp;
            float dtr = fmaf(xr.x, wv4.x, fmaf(xr.y, wv4.y, fmaf(xr.z, wv4.z, fmaf(xr.w, wv4.w, bias))));
            float dt = softplusf(dtr);
            Sdt += dt;
            int p = p_of(k, cc*TT + t);
            float u = xcb[(size_t)p*DI + d];
            float du = dt * u;
            float4 B0 = *(const float4*)(rp + 4);
            float4 B1 = *(const float4*)(rp + 8);
            float4 B2 = *(const float4*)(rp + 12);
            float4 B3 = *(const float4*)(rp + 16);
            float Bv[16] = {B0.x,B0.y,B0.z,B0.w, B1.x,B1.y,B1.z,B1.w,
                            B2.x,B2.y,B2.z,B2.w, B3.x,B3.y,B3.z,B3.w};
            float E[16];
            pow16(exp2f(-1.44269504f * dt), E);
            #pragma unroll
            for (int i = 0; i < 16; i++)
                h[i] = fmaf(h[i], E[i], du*Bv[i]);
        }
        size_t ob = ((size_t)bid)*2048 + d*16;
        float E[16];
        pow16(exp2f(-1.44269504f * Sdt), E);
        #pragma unroll
        for (int i = 0; i < 16; i++){
            Pbuf[ob + i] = E[i];
            Hbuf[ob + i] = h[i];
        }
    } else {
        float An2[16];
        #pragma unroll
        for (int i = 0; i < 16; i++) An2[i] = An[i] * 1.44269504f;
        for (int t = 0; t < TT; t++){
            const float* rp = sraw + t*XD;
            float4 xr = *(const float4*)rp;
            float dtr = fmaf(xr.x, wv4.x, fmaf(xr.y, wv4.y, fmaf(xr.z, wv4.z, fmaf(xr.w, wv4.w, bias))));
            float dt = softplusf(dtr);
            Sdt += dt;
            int p = p_of(k, cc*TT + t);
            float u = xcb[(size_t)p*DI + d];
            float du = dt * u;
            float4 B0 = *(const float4*)(rp + 4);
            float4 B1 = *(const float4*)(rp + 8);
            float4 B2 = *(const float4*)(rp + 12);
            float4 B3 = *(const float4*)(rp + 16);
            float Bv[16] = {B0.x,B0.y,B0.z,B0.w, B1.x,B1.y,B1.z,B1.w,
                            B2.x,B2.y,B2.z,B2.w, B3.x,B3.y,B3.z,B3.w};
            #pragma unroll
            for (int i = 0; i < 16; i++)
                h[i] = fmaf(h[i], exp2f(dt*An2[i]), du*Bv[i]);
        }
        size_t ob = ((size_t)bid)*2048 + d*16;
        #pragma unroll
        for (int i = 0; i < 16; i++){
            Pbuf[ob + i] = exp2f(An2[i] * Sdt);
            Hbuf[ob + i] = h[i];
        }
    }
}

// ---------------- K4b: chunk-boundary propagation
__global__ __launch_bounds__(256) void k4b_prop(
    const float* __restrict__ Pbuf, const float* __restrict__ Hbuf,
    float* __restrict__ hin_buf)
{
    int chain = blockIdx.x*256 + threadIdx.x;
    int bk = chain >> 11, s = chain & 2047;
    float hin = 0.f;
    for (int c = 0; c < GG; c++){
        size_t idx = ((size_t)(bk*GG + c))*2048 + s;
        hin_buf[idx] = hin;
        hin = fmaf(Pbuf[idx], hin, Hbuf[idx]);
    }
}

// ---------------- K4c (store mode): re-scan, write per-direction y buffer
__global__ __launch_bounds__(128, 4) void k4c_store(
    const float* __restrict__ xc, const float* __restrict__ xdbl,
    const float* __restrict__ dtw, const float* __restrict__ dtb,
    const float* __restrict__ A_logs, const float* __restrict__ Ds,
    const float* __restrict__ hin_buf,
    float* __restrict__ y0, float* __restrict__ y1,
    float* __restrict__ y2, float* __restrict__ y3)
{
    int bid = blockIdx.x;
    int cc = bid & 63, k = (bid >> 6) & 3, b = bid >> 8;
    int d = threadIdx.x;
    int kd = k*DI + d;
    float4 wv4 = *(const float4*)(dtw + kd*4);
    float bias = dtb[kd];
    float Dv = Ds[kd];
    float An[16];
    bool fast = true;
    {
        const float4* al = (const float4*)(A_logs + kd*16);
        #pragma unroll
        for (int i = 0; i < 4; i++){
            float4 a = al[i];
            An[i*4+0] = -__expf(a.x); An[i*4+1] = -__expf(a.y);
            An[i*4+2] = -__expf(a.z); An[i*4+3] = -__expf(a.w);
        }
        #pragma unroll
        for (int n = 0; n < 16; n++)
            fast = fast && (fabsf(An[n] + (float)(n+1)) < 1e-3f*(float)(n+1));
    }
    __shared__ float sraw[TT*XD];
    const float* src = xdbl + ((size_t)(b*KK + k)*LL + cc*TT)*XD;
    for (int i = threadIdx.x; i < TT*XD/4; i += 128)
        ((float4*)sraw)[i] = ((const float4*)src)[i];
    __syncthreads();

    const float* xcb = xc + (size_t)b*LL*DI;
    float* yk = (k == 0) ? y0 : (k == 1) ? y1 : (k == 2) ? y2 : y3;
    float* yb = yk + (size_t)b*LL*DI;
    float h[16];
    {
        const float4* hi = (const float4*)(hin_buf + ((size_t)bid)*2048 + d*16);
        #pragma unroll
        for (int i = 0; i < 4; i++){
            float4 a = hi[i];
            h[i*4+0] = a.x; h[i*4+1] = a.y; h[i*4+2] = a.z; h[i*4+3] = a.w;
        }
    }

    if (fast){
        for (int t = 0; t < TT; t++){
            const float* rp = sraw + t*XD;
            float4 xr = *(const float4*)rp;
            float dtr = fmaf(xr.x, wv4.x, fmaf(xr.y, wv4.y, fmaf(xr.z, wv4.z, fmaf(xr.w, wv4.w, bias))));
            float dt = softplusf(dtr);
            int p = p_of(k, cc*TT + t);
            float u = xcb[(size_t)p*DI + d];
            float du = dt * u;
            float4 B0 = *(const float4*)(rp + 4);
            float4 B1 = *(const float4*)(rp + 8);
            float4 B2 = *(const float4*)(rp + 12);
            float4 B3 = *(const float4*)(rp + 16);
            float Bv[16] = {B0.x,B0.y,B0.z,B0.w, B1.x,B1.y,B1.z,B1.w,
                            B2.x,B2.y,B2.z,B2.w, B3.x,B3.y,B3.z,B3.w};
            float4 C0 = *(const float4*)(rp + 20);
            float4 C1 = *(const float4*)(rp + 24);
            float4 C2 = *(const float4*)(rp + 28);
            float4 C3 = *(const float4*)(rp + 32);
            float Cv[16] = {C0.x,C0.y,C0.z,C0.w, C1.x,C1.y,C1.z,C1.w,
                            C2.x,C2.y,C2.z,C2.w, C3.x,C3.y,C3.z,C3.w};
            float E[16];
            pow16(exp2f(-1.44269504f * dt), E);
            float yv = Dv * u;
            #pragma unroll
            for (int i = 0; i < 16; i++){
                h[i] = fmaf(h[i], E[i], du*Bv[i]);
                yv = fmaf(h[i], Cv[i], yv);
            }
            yb[(size_t)p*DI + d] = yv;
        }
    } else {
        float An2[16];
        #pragma unroll
        for (int i = 0; i < 16; i++) An2[i] = An[i] * 1.44269504f;
        for (int t = 0; t < TT; t++){
            const float* rp = sraw + t*XD;
            float4 xr = *(const float4*)rp;
            float dtr = fmaf(xr.x, wv4.x, fmaf(xr.y, wv4.y, fmaf(xr.z, wv4.z, fmaf(xr.w, wv4.w, bias))));
            float dt = softplusf(dtr);
            int p = p_of(k, cc*TT + t);
            float u = xcb[(size_t)p*DI + d];
            float du = dt * u;
            float4 B0 = *(const float4*)(rp + 4);
            float4 B1 = *(const float4*)(rp + 8);
            float4 B2 = *(const float4*)(rp + 12);
            float4 B3 = *(const float4*)(rp + 16);
            float Bv[16] = {B0.x,B0.y,B0.z,B0.w, B1.x,B1.y,B1.z,B1.w,
                            B2.x,B2.y,B2.z,B2.w, B3.x,B3.y,B3.z,B3.w};
            float4 C0 = *(const float4*)(rp + 20);
            float4 C1 = *(const float4*)(rp + 24);
            float4 C2 = *(const float4*)(rp + 28);
            float4 C3 = *(const float4*)(rp + 32);
            float Cv[16] = {C0.x,C0.y,C0.z,C0.w, C1.x,C1.y,C1.z,C1.w,
                            C2.x,C2.y,C2.z,C2.w, C3.x,C3.y,C3.z,C3.w};
            float yv = Dv * u;
            #pragma unroll
            for (int i = 0; i < 16; i++){
                h[i] = fmaf(h[i], exp2f(dt*An2[i]), du*Bv[i]);
                yv = fmaf(h[i], Cv[i], yv);
            }
            yb[(size_t)p*DI + d] = yv;
        }
    }
}

// ---------------- K4c (atomic fallback, single y buffer)
__global__ __launch_bounds__(128, 4) void k4c_emit(
    const float* __restrict__ xc, const float* __restrict__ xdbl,
    const float* __restrict__ dtw, const float* __restrict__ dtb,
    const float* __restrict__ A_logs, const float* __restrict__ Ds,
    const float* __restrict__ hin_buf,
    float* __restrict__ y)
{
    int bid = blockIdx.x;
    int cc = bid & 63, k = (bid >> 6) & 3, b = bid >> 8;
    int d = threadIdx.x;
    int kd = k*DI + d;
    float4 wv4 = *(const float4*)(dtw + kd*4);
    float bias = dtb[kd];
    float Dv = Ds[kd];
    float An2[16];
    {
        const float4* al = (const float4*)(A_logs + kd*16);
        #pragma unroll
        for (int i = 0; i < 4; i++){
            float4 a = al[i];
            An2[i*4+0] = -__expf(a.x)*1.44269504f; An2[i*4+1] = -__expf(a.y)*1.44269504f;
            An2[i*4+2] = -__expf(a.z)*1.44269504f; An2[i*4+3] = -__expf(a.w)*1.44269504f;
        }
    }
    __shared__ float sraw[TT*XD];
    const float* src = xdbl + ((size_t)(b*KK + k)*LL + cc*TT)*XD;
    for (int i = threadIdx.x; i < TT*XD/4; i += 128)
        ((float4*)sraw)[i] = ((const float4*)src)[i];
    __syncthreads();

    const float* xcb = xc + (size_t)b*LL*DI;
    float* yb = y + (size_t)b*LL*DI;
    float h[16];
    {
        const float4* hi = (const float4*)(hin_buf + ((size_t)bid)*2048 + d*16);
        #pragma unroll
        for (int i = 0; i < 4; i++){
            float4 a = hi[i];
            h[i*4+0] = a.x; h[i*4+1] = a.y; h[i*4+2] = a.z; h[i*4+3] = a.w;
        }
    }
    for (int t = 0; t < TT; t++){
        const float* rp = sraw + t*XD;
        float4 xr = *(const float4*)rp;
        float dtr = fmaf(xr.x, wv4.x, fmaf(xr.y, wv4.y, fmaf(xr.z, wv4.z, fmaf(xr.w, wv4.w, bias))));
        float dt = softplusf(dtr);
        int p = p_of(k, cc*TT + t);
        float u = xcb[(size_t)p*DI + d];
        float du = dt * u;
        float4 B0 = *(const float4*)(rp + 4);
        float4 B1 = *(const float4*)(rp + 8);
        float4 B2 = *(const float4*)(rp + 12);
        float4 B3 = *(const float4*)(rp + 16);
        float Bv[16] = {B0.x,B0.y,B0.z,B0.w, B1.x,B1.y,B1.z,B1.w,
                        B2.x,B2.y,B2.z,B2.w, B3.x,B3.y,B3.z,B3.w};
        float4 C0 = *(const float4*)(rp + 20);
        float4 C1 = *(const float4*)(rp + 24);
        float4 C2 = *(const float4*)(rp + 28);
        float4 C3 = *(const float4*)(rp + 32);
        float Cv[16] = {C0.x,C0.y,C0.z,C0.w, C1.x,C1.y,C1.z,C1.w,
                        C2.x,C2.y,C2.z,C2.w, C3.x,C3.y,C3.z,C3.w};
        float yv = Dv * u;
        #pragma unroll
        for (int i = 0; i < 16; i++){
            h[i] = fmaf(h[i], exp2f(dt*An2[i]), du*Bv[i]);
            yv = fmaf(h[i], Cv[i], yv);
        }
        atomicAdd(&yb[(size_t)p*DI + d], yv);
    }
}

// ---------------- K4 serial fallback (used if ws too small)
__global__ __launch_bounds__(256) void k4_scan(
    const float* __restrict__ xc, const float* __restrict__ xdbl,
    const float* __restrict__ dtw, const float* __restrict__ dtb,
    const float* __restrict__ A_logs, const float* __restrict__ Ds,
    float* __restrict__ y)
{
    int bid = blockIdx.x;
    int b = bid >> 5, k = (bid >> 3) & 3, grp = bid & 7;
    int d0 = grp * 16;
    int tid = threadIdx.x;
    int wv = tid >> 6, lane = tid & 63, n = lane & 15, j = lane >> 4;
    int ch = wv*4 + j;
    int d = d0 + ch;
    int kd = k*DI + d;
    float An = -__expf(A_logs[kd*NN + n]);
    int ch_s = tid & 15;
    int kds = k*DI + d0 + ch_s;
    float w0s = dtw[kds*4+0], w1s = dtw[kds*4+1], w2s = dtw[kds*4+2], w3s = dtw[kds*4+3];
    float bs  = dtb[kds];
    float Dvs = Ds[kds];
    __shared__ float sraw[64*XD];
    __shared__ float sdd[64*16*2];
    __shared__ float sdy[64*17];
    const float* xdbase = xdbl + (size_t)(b*KK + k)*LL*XD;
    const float* xcb = xc + (size_t)b*LL*DI;
    float* yb = y + (size_t)b*LL*DI;
    float h = 0.f;
    for (int cc = 0; cc < 64; cc++){
        __syncthreads();
        const float* src = xdbase + (size_t)cc*64*XD;
        for (int i2 = tid; i2 < 576; i2 += 256)
            ((float4*)sraw)[i2] = ((const float4*)src)[i2];
        #pragma unroll
        for (int it = 0; it < 4; it++){
            int idx = tid + it*256;
            int t = idx >> 4;
            int pu = p_of(k, cc*64 + t);
            float u = xcb[(size_t)pu*DI + d0 + ch_s];
            float4 xr = *(const float4*)(src + t*XD);
            float dtr = fmaf(xr.x, w0s, fmaf(xr.y, w1s, fmaf(xr.z, w2s, fmaf(xr.w, w3s, bs))));
            float dt = softplusf(dtr);
            sdd[idx*2]     = dt;
            sdd[idx*2 + 1] = dt*u;
            sdy[t*17 + ch_s] = Dvs * u;
        }
        __syncthreads();
        #pragma unroll
        for (int tg = 0; tg < 4; tg++){
            float myv = 0.f;
            #pragma unroll
            for (int it = 0; it < 16; it++){
                int t = tg*16 + it;
                float dt = sdd[(t*16 + ch)*2];
                float du = sdd[(t*16 + ch)*2 + 1];
                float Bn = sraw[t*XD + 4 + n];
                float Cn = sraw[t*XD + 20 + n];
                float e = __expf(dt * An);
                h = fmaf(h, e, du * Bn);
                float yv = h * Cn;
                yv = dpp_xadd<0xB1>(yv);
                yv = dpp_xadd<0x4E>(yv);
                yv = dpp_xadd<0x141>(yv);
                yv = dpp_xadd<0x140>(yv);
                if (it == n) myv = yv;
            }
            int t = tg*16 + n;
            float yt = myv + sdy[t*17 + ch];
            int p = p_of(k, cc*64 + t);
            atomicAdd(&yb[(size_t)p*DI + d], yt);
        }
    }
}

// ---------------- K5: LN(DI)*silu(z) + out_proj + residual + fused channel-LN
// nsum=4: y = y0+y1+y2+y3 (store mode); nsum=1: y = y0
__global__ __launch_bounds__(256) void k5_out(
    const float* __restrict__ y0s, const float* __restrict__ y1s,
    const float* __restrict__ y2s, const float* __restrict__ y3s,
    int nsum,
    const float* __restrict__ zs,
    const float* __restrict__ on_g, const float* __restrict__ on_b,
    const float* __restrict__ opw,  // (64,128)
    const float* __restrict__ opb,
    const float* __restrict__ x,    // (B,C,L)
    const float* __restrict__ cn_g, const float* __restrict__ cn_b,
    float* __restrict__ xo, float* __restrict__ cl)
{
    int bid = blockIdx.x;
    int b = bid >> 6, p0 = (bid & 63)*64;
    int tid = threadIdx.x;

    __shared__ float vT[128*68];
    __shared__ float wT[128*68];
    __shared__ float gb[256];
    __shared__ float ob[64];
    __shared__ float cgb[128];
    __shared__ float red[2048];
    __shared__ float mv[128];

    gb[tid] = (tid < 128) ? on_g[tid] : on_b[tid - 128];
    if (tid < 64) ob[tid] = opb[tid];
    if (tid >= 128 && tid < 256) cgb[tid-128] = (tid < 192) ? cn_g[tid-128] : cn_b[tid-192];

    #pragma unroll
    for (int it = 0; it < 8; it++){
        int i = tid + it*256;
        int c = i >> 5, jq = i & 31;
        float4 wv = *(const float4*)(opw + c*128 + jq*4);
        wT[(jq*4+0)*68 + c] = wv.x;
        wT[(jq*4+1)*68 + c] = wv.y;
        wT[(jq*4+2)*68 + c] = wv.z;
        wT[(jq*4+3)*68 + c] = wv.w;
    }

    int pix = tid >> 2, q = tid & 3;
    size_t base = ((size_t)(b*LL) + p0 + pix)*DI + q*32;
    float yv[32];
    {
        float s = 0.f, sq = 0.f;
        if (nsum == 4){
            const float4* a4 = (const float4*)(y0s + base);
            const float4* b4 = (const float4*)(y1s + base);
            const float4* c4 = (const float4*)(y2s + base);
            const float4* d4 = (const float4*)(y3s + base);
            #pragma unroll
            for (int i = 0; i < 8; i++){
                float4 a = a4[i], bb = b4[i], c = c4[i], dd = d4[i];
                float4 v;
                v.x = (a.x + bb.x) + (c.x + dd.x);
                v.y = (a.y + bb.y) + (c.y + dd.y);
                v.z = (a.z + bb.z) + (c.z + dd.z);
                v.w = (a.w + bb.w) + (c.w + dd.w);
                yv[i*4+0] = v.x; yv[i*4+1] = v.y; yv[i*4+2] = v.z; yv[i*4+3] = v.w;
                s += v.x + v.y + v.z + v.w;
                sq = fmaf(v.x,v.x, fmaf(v.y,v.y, fmaf(v.z,v.z, fmaf(v.w,v.w, sq))));
            }
        } else {
            const float4* a4 = (const float4*)(y0s + base);
            #pragma unroll
            for (int i = 0; i < 8; i++){
                float4 a = a4[i];
                yv[i*4+0] = a.x; yv[i*4+1] = a.y; yv[i*4+2] = a.z; yv[i*4+3] = a.w;
                s += a.x + a.y + a.z + a.w;
                sq = fmaf(a.x,a.x, fmaf(a.y,a.y, fmaf(a.z,a.z, fmaf(a.w,a.w, sq))));
            }
        }
        red[tid*2] = s; red[tid*2+1] = sq;
    }
    __syncthreads();
    if (tid < 64){
        float s = red[tid*8] + red[tid*8+2] + red[tid*8+4] + red[tid*8+6];
        float sq = red[tid*8+1] + red[tid*8+3] + red[tid*8+5] + red[tid*8+7];
        float mean = s * (1.f/128.f);
        float var  = sq * (1.f/128.f) - mean*mean;
        mv[tid*2] = mean; mv[tid*2+1] = rsqrtf(var + 1e-5f);
    }
    __syncthreads();
    {
        float mean = mv[pix*2], rstd = mv[pix*2+1];
        const float4* z4 = (const float4*)(zs + base);
        #pragma unroll
        for (int i = 0; i < 8; i++){
            float4 zz = z4[i];
            float zv[4] = {zz.x, zz.y, zz.z, zz.w};
            #pragma unroll
            for (int jj = 0; jj < 4; jj++){
                int dd = q*32 + i*4 + jj;
                float vn = (yv[i*4+jj] - mean)*rstd*gb[dd] + gb[128+dd];
                vT[dd*68 + pix] = vn * zv[jj];
            }
        }
    }
    __syncthreads();

    int pt = tid >> 4, ot = tid & 15;
    float acc[4][4];
    #pragma unroll
    for (int j = 0; j < 4; j++)
        #pragma unroll
        for (int i2 = 0; i2 < 4; i2++) acc[j][i2] = 0.f;

    #pragma unroll 4
    for (int k = 0; k < 128; k++){
        float4 rv = *(const float4*)(vT + k*68 + pt*4);
        float4 wv = *(const float4*)(wT + k*68 + ot*4);
        acc[0][0] = fmaf(wv.x, rv.x, acc[0][0]); acc[0][1] = fmaf(wv.x, rv.y, acc[0][1]);
        acc[0][2] = fmaf(wv.x, rv.z, acc[0][2]); acc[0][3] = fmaf(wv.x, rv.w, acc[0][3]);
        acc[1][0] = fmaf(wv.y, rv.x, acc[1][0]); acc[1][1] = fmaf(wv.y, rv.y, acc[1][1]);
        acc[1][2] = fmaf(wv.y, rv.z, acc[1][2]); acc[1][3] = fmaf(wv.y, rv.w, acc[1][3]);
        acc[2][0] = fmaf(wv.z, rv.x, acc[2][0]); acc[2][1] = fmaf(wv.z, rv.y, acc[2][1]);
        acc[2][2] = fmaf(wv.z, rv.z, acc[2][2]); acc[2][3] = fmaf(wv.z, rv.w, acc[2][3]);
        acc[3][0] = fmaf(wv.w, rv.x, acc[3][0]); acc[3][1] = fmaf(wv.w, rv.y, acc[3][1]);
        acc[3][2] = fmaf(wv.w, rv.z, acc[3][2]); acc[3][3] = fmaf(wv.w, rv.w, acc[3][3]);
    }

    #pragma unroll
    for (int jj = 0; jj < 4; jj++){
        int c = ot*4 + jj;
        float4 xr = *(const float4*)(x + ((size_t)(b*CC + c))*LL + p0 + pt*4);
        acc[jj][0] += ob[c] + xr.x;
        acc[jj][1] += ob[c] + xr.y;
        acc[jj][2] += ob[c] + xr.z;
        acc[jj][3] += ob[c] + xr.w;
    }
    #pragma unroll
    for (int i2 = 0; i2 < 4; i2++){
        float4 v = make_float4(acc[0][i2], acc[1][i2], acc[2][i2], acc[3][i2]);
        *(float4*)(xo + ((size_t)(b*LL) + p0 + pt*4 + i2)*CC + ot*4) = v;
    }

    __syncthreads();
    #pragma unroll
    for (int i2 = 0; i2 < 4; i2++){
        float s = acc[0][i2] + acc[1][i2] + acc[2][i2] + acc[3][i2];
        float sq = fmaf(acc[0][i2],acc[0][i2], fmaf(acc[1][i2],acc[1][i2],
                   fmaf(acc[2][i2],acc[2][i2], acc[3][i2]*acc[3][i2])));
        red[(pt*4 + i2)*16 + ot] = s;
        red[1024 + (pt*4 + i2)*16 + ot] = sq;
    }
    __syncthreads();
    if (tid < 64){
        float s = 0.f, sq = 0.f;
        #pragma unroll
        for (int o = 0; o < 16; o++){
            s += red[tid*16 + o];
            sq += red[1024 + tid*16 + o];
        }
        float mean = s * (1.f/64.f);
        float var  = sq * (1.f/64.f) - mean*mean;
        mv[tid*2] = mean; mv[tid*2+1] = rsqrtf(var + 1e-6f);
    }
    __syncthreads();
    #pragma unroll
    for (int i2 = 0; i2 < 4; i2++){
        float mean = mv[(pt*4+i2)*2], rstd = mv[(pt*4+i2)*2+1];
        float4 v;
        v.x = (acc[0][i2] - mean)*rstd*cgb[ot*4+0] + cgb[64+ot*4+0];
        v.y = (acc[1][i2] - mean)*rstd*cgb[ot*4+1] + cgb[64+ot*4+1];
        v.z = (acc[2][i2] - mean)*rstd*cgb[ot*4+2] + cgb[64+ot*4+2];
        v.w = (acc[3][i2] - mean)*rstd*cgb[ot*4+3] + cgb[64+ot*4+3];
        *(float4*)(cl + ((size_t)(b*LL) + p0 + pt*4 + i2)*CC + ot*4) = v;
    }
}

// ---------------- K7: max pools 2/4/8 for SAFM branches 1..3
__global__ __launch_bounds__(256) void k7_pools(const float* __restrict__ cl, float* __restrict__ pools)
{
    int idx = blockIdx.x*256 + threadIdx.x;
    int g, S, base;
    if (idx < 131072)      { g = 1; S = 32; base = 0; }
    else if (idx < 163840) { g = 2; S = 16; base = 131072; idx -= 131072; }
    else if (idx < 172032) { g = 3; S = 8;  base = 163840; idx -= 163840; }
    else return;
    int pw = idx % S; idx /= S;
    int ph = idx % S; idx /= S;
    int j = idx & 15; int b = idx >> 4;
    int kk = 64 / S;
    int c = g*16 + j;
    float m = -1e30f;
    for (int dy = 0; dy < kk; dy++)
        for (int dx = 0; dx < kk; dx++){
            int h = ph*kk + dy, w = pw*kk + dx;
            m = fmaxf(m, cl[((size_t)(b*LL) + h*64 + w)*CC + c]);
        }
    pools[base + ((size_t)(b*16 + j)*S + ph)*S + pw] = m;
}

// ---------------- K8: SAFM branch depthwise convs -> cat (B,L,C)
__global__ __launch_bounds__(256) void k8_mfr(
    const float* __restrict__ cl, const float* __restrict__ pools,
    const float* __restrict__ mfr_w,  // (4,16,3,3)
    const float* __restrict__ mfr_b,  // (4,16)
    float* __restrict__ cat)
{
    int idx = blockIdx.x*256 + threadIdx.x;
    int c = idx & 63; int bp = idx >> 6;
    int p = bp & 4095, b = bp >> 12;
    int g = c >> 4, j = c & 15;
    int h = p >> 6, w = p & 63;
    float acc = mfr_b[g*16 + j];
    const float* wr = mfr_w + (g*16 + j)*9;
    if (g == 0){
        #pragma unroll
        for (int ky = 0; ky < 3; ky++){
            int hh = h + ky - 1; if ((unsigned)hh >= 64u) continue;
            #pragma unroll
            for (int kx = 0; kx < 3; kx++){
                int ww = w + kx - 1; if ((unsigned)ww >= 64u) continue;
                acc = fmaf(cl[((size_t)(b*LL) + hh*64 + ww)*CC + c], wr[ky*3 + kx], acc);
            }
        }
    } else {
        int S = 64 >> g;
        int ph = h >> g, pw = w >> g;
        int base = (g == 1) ? 0 : ((g == 2) ? 131072 : 163840);
        const float* P = pools + base + (size_t)(b*16 + j)*S*S;
        #pragma unroll
        for (int ky = 0; ky < 3; ky++){
            int hh = ph + ky - 1; if ((unsigned)hh >= (unsigned)S) continue;
            #pragma unroll
            for (int kx = 0; kx < 3; kx++){
                int ww = pw + kx - 1; if ((unsigned)ww >= (unsigned)S) continue;
                acc = fmaf(P[hh*S + ww], wr[ky*3 + kx], acc);
            }
        }
    }
    cat[idx] = acc;
}

// ---------------- K9: 1x1 agg + GELU*cl + residual, tiled GEMM -> out (B,C,L)
__global__ __launch_bounds__(256) void k9_agg(
    const float* __restrict__ cat, const float* __restrict__ cl, const float* __restrict__ xo,
    const float* __restrict__ agw,   // (64,64)
    const float* __restrict__ agb,
    float* __restrict__ out)
{
    int bid = blockIdx.x;
    int b = bid >> 6, p0 = (bid & 63)*64;
    int tid = threadIdx.x;

    __shared__ float catT[64*68];
    __shared__ float wT[64*68];
    __shared__ float ab[64];

    if (tid < 64) ab[tid] = agb[tid];
    #pragma unroll
    for (int it = 0; it < 4; it++){
        int i = tid + it*256;
        int pix = i >> 4, cq = i & 15;
        float4 v = *(const float4*)(cat + ((size_t)(b*LL) + p0 + pix)*CC + cq*4);
        catT[(cq*4+0)*68 + pix] = v.x;
        catT[(cq*4+1)*68 + pix] = v.y;
        catT[(cq*4+2)*68 + pix] = v.z;
        catT[(cq*4+3)*68 + pix] = v.w;
        int o = i >> 4;
        float4 wv = *(const float4*)(agw + o*64 + cq*4);
        wT[(cq*4+0)*68 + o] = wv.x;
        wT[(cq*4+1)*68 + o] = wv.y;
        wT[(cq*4+2)*68 + o] = wv.z;
        wT[(cq*4+3)*68 + o] = wv.w;
    }
    __syncthreads();

    int pt = tid >> 4, ot = tid & 15;
    float acc[4][4];
    #pragma unroll
    for (int j = 0; j < 4; j++)
        #pragma unroll
        for (int i2 = 0; i2 < 4; i2++) acc[j][i2] = 0.f;

    #pragma unroll 4
    for (int k = 0; k < 64; k++){
        float4 rv = *(const float4*)(catT + k*68 + pt*4);
        float4 wv = *(const float4*)(wT + k*68 + ot*4);
        acc[0][0] = fmaf(wv.x, rv.x, acc[0][0]); acc[0][1] = fmaf(wv.x, rv.y, acc[0][1]);
        acc[0][2] = fmaf(wv.x, rv.z, acc[0][2]); acc[0][3] = fmaf(wv.x, rv.w, acc[0][3]);
        acc[1][0] = fmaf(wv.y, rv.x, acc[1][0]); acc[1][1] = fmaf(wv.y, rv.y, acc[1][1]);
        acc[1][2] = fmaf(wv.y, rv.z, acc[1][2]); acc[1][3] = fmaf(wv.y, rv.w, acc[1][3]);
        acc[2][0] = fmaf(wv.z, rv.x, acc[2][0]); acc[2][1] = fmaf(wv.z, rv.y, acc[2][1]);
        acc[2][2] = fmaf(wv.z, rv.z, acc[2][2]); acc[2][3] = fmaf(wv.z, rv.w, acc[2][3]);
        acc[3][0] = fmaf(wv.w, rv.x, acc[3][0]); acc[3][1] = fmaf(wv.w, rv.y, acc[3][1]);
        acc[3][2] = fmaf(wv.w, rv.z, acc[3][2]); acc[3][3] = fmaf(wv.w, rv.w, acc[3][3]);
    }

    float res[4][4];
    #pragma unroll
    for (int i2 = 0; i2 < 4; i2++){
        size_t prow = ((size_t)(b*LL) + p0 + pt*4 + i2)*CC + ot*4;
        float4 clv = *(const float4*)(cl + prow);
        float4 xov = *(const float4*)(xo + prow);
        float cla[4] = {clv.x, clv.y, clv.z, clv.w};
        float xoa[4] = {xov.x, xov.y, xov.z, xov.w};
        #pragma unroll
        for (int jj = 0; jj < 4; jj++){
            float av = acc[jj][i2] + ab[ot*4 + jj];
            float gl = 0.5f*av*(1.f + erff(av*0.70710678118f));
            res[jj][i2] = xoa[jj] + gl*cla[jj];
        }
    }
    #pragma unroll
    for (int jj = 0; jj < 4; jj++){
        int o = ot*4 + jj;
        float4 v = make_float4(res[jj][0], res[jj][1], res[jj][2], res[jj][3]);
        *(float4*)(out + ((size_t)(b*CC + o))*LL + p0 + pt*4) = v;
    }
}

extern "C" void kernel_launch(void* const* d_in, const int* in_sizes, int n_in,
                              void* d_out, int out_size, void* d_ws, size_t ws_size,
                              hipStream_t stream)
{
    const float* x       = (const float*)d_in[0];
    const float* ln1_g   = (const float*)d_in[1];
    const float* ln1_b   = (const float*)d_in[2];
    const float* ipw     = (const float*)d_in[3];
    const float* ipb     = (const float*)d_in[4];
    const float* conv_w  = (const float*)d_in[5];
    const float* conv_b  = (const float*)d_in[6];
    const float* xpw     = (const float*)d_in[7];
    const float* dtw     = (const float*)d_in[8];
    const float* dtb     = (const float*)d_in[9];
    const float* A_logs  = (const float*)d_in[10];
    const float* Ds      = (const float*)d_in[11];
    const float* on_g    = (const float*)d_in[12];
    const float* on_b    = (const float*)d_in[13];
    const float* opw     = (const float*)d_in[14];
    const float* opb     = (const float*)d_in[15];
    const float* mfr_w   = (const float*)d_in[16];
    const float* mfr_b   = (const float*)d_in[17];
    const float* agw     = (const float*)d_in[18];
    const float* agb     = (const float*)d_in[19];
    const float* cn_g    = (const float*)d_in[20];
    const float* cn_b    = (const float*)d_in[21];
    float* out = (float*)d_out;

    float* ws = (float*)d_ws;
    float* xi    = ws;               // reused as y0
    float* zs    = ws + 4194304;     // reused as cat
    float* xc    = ws + 8388608;     // reused as xo + pools
    float* xdbl  = ws + 12582912;    // reused as cl
    float* y0    = xi;
    float* xo    = xc;
    float* pools = xc + 2097152;
    float* cl    = xdbl;
    float* cat   = zs;
    float* Pbuf  = ws + 17301504;    // reused as y1 after k4b
    float* Hbuf  = ws + 21495808;    // reused as y2 after k4b
    float* hinb  = ws + 25690112;
    float* y3    = ws + 29884416;    // store mode only
    bool par  = ws_size >= (size_t)29884416 * 4;
    bool par4 = ws_size >= (size_t)34078720 * 4;
    float* y1 = Pbuf;
    float* y2 = Hbuf;

    // SS2D
    hipLaunchKernelGGL(k1_ln_inproj, dim3(BB*64), dim3(256), 0, stream,
                       x, ln1_g, ln1_b, ipw, ipb, xi, zs);
    hipLaunchKernelGGL(k2_dwconv, dim3(BB*LL*DI/1024), dim3(256), 0, stream,
                       xi, conv_w, conv_b, xc);
    hipLaunchKernelGGL(k3_xdbl, dim3(BB*64), dim3(256), 0, stream,
                       xc, xpw, xdbl);
    int nsum = 1;
    if (par){
        hipLaunchKernelGGL(k4a_local, dim3(BB*KK*GG), dim3(128), 0, stream,
                           xc, xdbl, dtw, dtb, A_logs, Pbuf, Hbuf);
        hipLaunchKernelGGL(k4b_prop, dim3(256), dim3(256), 0, stream,
                           Pbuf, Hbuf, hinb);
        if (par4){
            nsum = 4;
            hipLaunchKernelGGL(k4c_store, dim3(BB*KK*GG), dim3(128), 0, stream,
                               xc, xdbl, dtw, dtb, A_logs, Ds, hinb, y0, y1, y2, y3);
        } else {
            hipMemsetAsync(y0, 0, (size_t)BB*LL*DI*sizeof(float), stream);
            hipLaunchKernelGGL(k4c_emit, dim3(BB*KK*GG), dim3(128), 0, stream,
                               xc, xdbl, dtw, dtb, A_logs, Ds, hinb, y0);
        }
    } else {
        hipMemsetAsync(y0, 0, (size_t)BB*LL*DI*sizeof(float), stream);
        hipLaunchKernelGGL(k4_scan, dim3(256), dim3(256), 0, stream,
                           xc, xdbl, dtw, dtb, A_logs, Ds, y0);
    }
    hipLaunchKernelGGL(k5_out, dim3(BB*64), dim3(256), 0, stream,
                       y0, y1, y2, y3, nsum, zs, on_g, on_b, opw, opb, x, cn_g, cn_b, xo, cl);
    // SAFM (k6 fused into k5)
    hipLaunchKernelGGL(k7_pools, dim3((172032 + 255)/256), dim3(256), 0, stream,
                       cl, pools);
    hipLaunchKernelGGL(k8_mfr, dim3(BB*LL*CC/256), dim3(256), 0, stream,
                       cl, pools, mfr_w, mfr_b, cat);
    hipLaunchKernelGGL(k9_agg, dim3(BB*64), dim3(256), 0, stream,
                       cat, cl, xo, agw, agb, out);
}